// Round 1
// baseline (1746.384 us; speedup 1.0000x reference)
//
#include <hip/hip_runtime.h>

#define DIMC 256
#define NPIX 14400      // 120*120
#define IMGW 120
#define IMGH 120

// ---- template weights (compile-time constants; match _templates()) ----
static constexpr float NEG  = -0.5f;
static constexpr float POS  = (float)(4.0 / 3.0);
static constexpr float NOR  = -0.375f;
static constexpr float CNOR = 4.0f;

// TW[i][off], off = dy*3+dx  (cross-correlation, SAME padding)
__device__ constexpr float TW[9][9] = {
  {NOR,NOR,NOR,  NOR,CNOR,NOR, NOR,NOR,NOR},
  {NEG,POS,NEG,  NEG,POS,NEG,  NEG,POS,NEG},
  {NEG,NEG,NEG,  POS,POS,POS,  NEG,NEG,NEG},
  {POS,NEG,NEG,  NEG,POS,NEG,  NEG,NEG,POS},
  {NEG,NEG,POS,  NEG,POS,NEG,  POS,NEG,NEG},
  {NEG,POS,NEG,  POS,POS,NEG,  NEG,NEG,NEG},
  {NEG,POS,NEG,  NEG,POS,POS,  NEG,NEG,NEG},
  {NEG,NEG,NEG,  POS,POS,NEG,  NEG,POS,NEG},
  {NEG,NEG,NEG,  NEG,POS,POS,  NEG,POS,NEG},
};

// ---------------- K1: fused triple projection ----------------
// O[d][tok] = sum_ch W[d][ch] * x[ch][tok]   (per batch)
// grid: (225 token tiles of 64, 4 batches, 12 = mat*4 + dtile)
__global__ __launch_bounds__(256) void proj_kernel(
    const float* __restrict__ x,
    const float* __restrict__ Wk, const float* __restrict__ Wv,
    const float* __restrict__ Wq,
    float* __restrict__ Xq, float* __restrict__ Xk, float* __restrict__ Xv)
{
  const int tb = blockIdx.x;
  const int b  = blockIdx.y;
  const int z  = blockIdx.z;
  const int mat = z >> 2, dt = z & 3;
  const int t0 = tb * 64, d0 = dt * 64;

  const float* W = (mat == 0) ? Wq : (mat == 1) ? Wk : Wv;
  float* O       = (mat == 0) ? Xq : (mat == 1) ? Xk : Xv;
  const float sc = (mat == 0) ? 0.17677669529663687f : 1.0f;  // 32^-0.5 for Q

  __shared__ __align__(16) float xs[16 * 64];    // [r][col]
  __shared__ __align__(16) float wsl[16 * 68];   // [r][j] (W tile transposed)

  const int tid = threadIdx.x;
  const int tx = tid & 15, ty = tid >> 4;

  float4 acc[4];
  #pragma unroll
  for (int j = 0; j < 4; ++j) acc[j] = make_float4(0.f, 0.f, 0.f, 0.f);

  const float* xb = x + (size_t)b * DIMC * NPIX + t0;

  for (int c0 = 0; c0 < 256; c0 += 16) {
    #pragma unroll
    for (int i = 0; i < 4; ++i) {
      int f = tid + 256 * i;
      int r = f >> 6, col = f & 63;
      xs[r * 64 + col] = xb[(size_t)(c0 + r) * NPIX + col];
    }
    #pragma unroll
    for (int i = 0; i < 4; ++i) {
      int f = tid + 256 * i;
      int j = f >> 4, chl = f & 15;
      wsl[chl * 68 + j] = W[(d0 + j) * 256 + c0 + chl];
    }
    __syncthreads();
    #pragma unroll
    for (int r = 0; r < 16; ++r) {
      float4 a4 = *(const float4*)&xs[r * 64 + tx * 4];
      float4 b4 = *(const float4*)&wsl[r * 68 + ty * 4];
      acc[0].x += b4.x * a4.x; acc[0].y += b4.x * a4.y; acc[0].z += b4.x * a4.z; acc[0].w += b4.x * a4.w;
      acc[1].x += b4.y * a4.x; acc[1].y += b4.y * a4.y; acc[1].z += b4.y * a4.z; acc[1].w += b4.y * a4.w;
      acc[2].x += b4.z * a4.x; acc[2].y += b4.z * a4.y; acc[2].z += b4.z * a4.z; acc[2].w += b4.z * a4.w;
      acc[3].x += b4.w * a4.x; acc[3].y += b4.w * a4.y; acc[3].z += b4.w * a4.z; acc[3].w += b4.w * a4.w;
    }
    __syncthreads();
  }

  float* Ob = O + (size_t)b * DIMC * NPIX + t0;
  #pragma unroll
  for (int j = 0; j < 4; ++j) {
    float4 v = make_float4(acc[j].x * sc, acc[j].y * sc, acc[j].z * sc, acc[j].w * sc);
    *(float4*)&Ob[(size_t)(d0 + ty * 4 + j) * NPIX + tx * 4] = v;
  }
}

// ---------------- K2: fused window attention ----------------
// grid: 2304 windows (b*576 + by*24 + bx), 256 threads
__global__ __launch_bounds__(256) void attn_kernel(
    const float* Xq,   // aliases d_out (also AO destination)
    const float* __restrict__ Xk,
    const float* __restrict__ Xv,
    float* AO)
{
  __shared__ __align__(16) float lds[18816];
  float* buf_qo = lds;            // 6400: [q][c]  (Q in, attn-out out; per-head slices)
  float* xkh    = lds + 6400;     // 1764: [p'][dl] stride 36
  float* xvh    = lds + 8164;     // 1764
  float* Sm     = lds + 9928;     // 1300: [q][p'] stride 52
  float* Pm     = lds + 11228;    // 6250: [(q*25+kp)*10 + i]
  float* Am     = lds + 17478;    // 1300: [q][p'] stride 52
  float* rinv   = lds + 18778;    // 32

  const int tid = threadIdx.x;
  const int wz = blockIdx.x;
  const int b = wz / 576;
  const int rr = wz % 576;
  const int by = rr / 24, bx = rr % 24;
  const int y0 = by * 5, x0 = bx * 5;
  const size_t bbase = (size_t)b * DIMC * NPIX;

  // Ph0: load Q window -> buf_qo
  #pragma unroll
  for (int i = 0; i < 25; ++i) {
    int f = tid + 256 * i;          // 6400 exactly
    int wx = f % 5; int t1 = f / 5; int wy = t1 % 5; int c = t1 / 5;
    buf_qo[(wy * 5 + wx) * 256 + c] =
        Xq[bbase + (size_t)c * NPIX + (y0 + wy) * IMGW + (x0 + wx)];
  }
  __syncthreads();

  for (int h = 0; h < 8; ++h) {
    // Ph1: load per-head K,V halo [49 pix][32 dims]
    for (int i = 0; i < 7; ++i) {
      int f = tid + 256 * i;
      if (f < 1568) {
        int hx = f % 7; int t1 = f / 7; int hy = t1 % 7; int dl = t1 / 7;
        int gy = y0 - 1 + hy, gx = x0 - 1 + hx;
        float vk = 0.f, vv = 0.f;
        if (gy >= 0 && gy < IMGH && gx >= 0 && gx < IMGW) {
          size_t gidx = bbase + (size_t)(h * 32 + dl) * NPIX + gy * IMGW + gx;
          vk = Xk[gidx];
          vv = Xv[gidx];
        }
        int p = hy * 7 + hx;
        xkh[p * 36 + dl] = vk;
        xvh[p * 36 + dl] = vv;
      }
    }
    __syncthreads();

    // Ph2: S[q][p'] = Q[q] . Xk_halo[p']   (head slice)
    if (tid < 245) {
      int pp = tid % 49, qg = tid / 49;
      float4 kk[8];
      #pragma unroll
      for (int j = 0; j < 8; ++j) kk[j] = *(const float4*)&xkh[pp * 36 + j * 4];
      #pragma unroll
      for (int qi = 0; qi < 5; ++qi) {
        int q = qg * 5 + qi;
        const float* qp = &buf_qo[q * 256 + h * 32];
        float acc = 0.f;
        #pragma unroll
        for (int j = 0; j < 8; ++j) {
          float4 a = *(const float4*)&qp[j * 4];
          acc += a.x * kk[j].x + a.y * kk[j].y + a.z * kk[j].z + a.w * kk[j].w;
        }
        Sm[q * 52 + pp] = acc;
      }
    }
    __syncthreads();

    // Ph3: logits via template expansion (compile-time weights)
    for (int it = 0; it < 3; ++it) {
      int f = tid + 256 * it;
      if (f < 625) {
        int q = f / 25, kp = f % 25;
        int ky = kp / 5, kx = kp % 5;
        float s9[9];
        #pragma unroll
        for (int dy = 0; dy < 3; ++dy)
          #pragma unroll
          for (int dx = 0; dx < 3; ++dx)
            s9[dy * 3 + dx] = Sm[q * 52 + (ky + dy) * 7 + (kx + dx)];
        #pragma unroll
        for (int i = 0; i < 9; ++i) {
          float l = 0.f;
          #pragma unroll
          for (int o = 0; o < 9; ++o) l += TW[i][o] * s9[o];
          Pm[(q * 25 + kp) * 10 + i] = l;
        }
      }
    }
    __syncthreads();

    // Ph3b: softmax (rowmax, exp, rowsum) — 8-lane teams per q row
    if (tid < 200) {
      int q = tid >> 3, s = tid & 7;
      float m = -1e30f;
      for (int k = s; k < 225; k += 8) {
        int i = k / 25, kp = k % 25;
        m = fmaxf(m, Pm[(q * 25 + kp) * 10 + i]);
      }
      #pragma unroll
      for (int o = 4; o >= 1; o >>= 1) m = fmaxf(m, __shfl_xor(m, o, 8));
      float sum = 0.f;
      for (int k = s; k < 225; k += 8) {
        int i = k / 25, kp = k % 25;
        int idx = (q * 25 + kp) * 10 + i;
        float p = __expf(Pm[idx] - m);
        Pm[idx] = p;
        sum += p;
      }
      #pragma unroll
      for (int o = 4; o >= 1; o >>= 1) sum += __shfl_xor(sum, o, 8);
      if (s == 0) rinv[q] = 1.0f / sum;
    }
    __syncthreads();

    // Ph4: fold P back onto halo: A[q][p'] = sum_i sum_off TW[i][off] P[q][i][kp]
    for (int it = 0; it < 5; ++it) {
      int f = tid + 256 * it;
      if (f < 1225) {
        int q = f / 49, pp = f % 49;
        int hy = pp / 7, hx = pp % 7;
        float acc = 0.f;
        #pragma unroll
        for (int dy = 0; dy < 3; ++dy) {
          int ky = hy - dy;
          if ((unsigned)ky < 5u) {
            #pragma unroll
            for (int dx = 0; dx < 3; ++dx) {
              int kx = hx - dx;
              if ((unsigned)kx < 5u) {
                const float* pb = &Pm[(q * 25 + ky * 5 + kx) * 10];
                const int o = dy * 3 + dx;
                #pragma unroll
                for (int i = 0; i < 9; ++i) acc += TW[i][o] * pb[i];
              }
            }
          }
        }
        Am[q * 52 + pp] = acc * rinv[q];
      }
    }
    __syncthreads();

    // Ph5: PV: out[q][hdim] = sum_p' A[q][p'] * Xv_halo[p'][hdim]
    if (tid < 200) {
      int q = tid >> 3, dg = tid & 7;
      float4 acc = make_float4(0.f, 0.f, 0.f, 0.f);
      for (int pp = 0; pp < 49; ++pp) {
        float a = Am[q * 52 + pp];
        float4 v = *(const float4*)&xvh[pp * 36 + dg * 4];
        acc.x += a * v.x; acc.y += a * v.y; acc.z += a * v.z; acc.w += a * v.w;
      }
      *(float4*)&buf_qo[q * 256 + h * 32 + dg * 4] = acc;
    }
    __syncthreads();
  }

  // Ph6: write attention output (pre-projection) back to global (aliases Xq/d_out)
  #pragma unroll
  for (int i = 0; i < 25; ++i) {
    int f = tid + 256 * i;
    int wx = f % 5; int t1 = f / 5; int wy = t1 % 5; int c = t1 / 5;
    AO[bbase + (size_t)c * NPIX + (y0 + wy) * IMGW + (x0 + wx)] =
        buf_qo[(wy * 5 + wx) * 256 + c];
  }
}

// ---------------- K3: output projection (in-place on d_out) ----------------
// O[d][tok] = sum_ch Wout[d][ch]*AO[ch][tok] + bout[d]; block: all 256 d x 64 tok
__global__ __launch_bounds__(256) void outproj_kernel(
    const float* AO, const float* __restrict__ Wout,
    const float* __restrict__ bout, float* O)
{
  const int tb = blockIdx.x, b = blockIdx.y;
  const int t0 = tb * 64;
  __shared__ __align__(16) float as[16 * 64];
  __shared__ __align__(16) float wsl[16 * 260];
  const int tid = threadIdx.x;
  const int tx = tid & 15, ty = tid >> 4;

  float4 acc4[16];
  #pragma unroll
  for (int j = 0; j < 16; ++j) acc4[j] = make_float4(0.f, 0.f, 0.f, 0.f);

  const float* ab = AO + (size_t)b * DIMC * NPIX + t0;

  for (int c0 = 0; c0 < 256; c0 += 16) {
    #pragma unroll
    for (int i = 0; i < 4; ++i) {
      int f = tid + 256 * i;
      int r = f >> 6, col = f & 63;
      as[r * 64 + col] = ab[(size_t)(c0 + r) * NPIX + col];
    }
    #pragma unroll
    for (int i = 0; i < 16; ++i) {
      int f = tid + 256 * i;
      int d = f >> 4, r = f & 15;
      wsl[r * 260 + d] = Wout[d * 256 + c0 + r];
    }
    __syncthreads();
    #pragma unroll
    for (int r = 0; r < 16; ++r) {
      float4 a4 = *(const float4*)&as[r * 64 + tx * 4];
      #pragma unroll
      for (int jj = 0; jj < 4; ++jj) {
        float4 w4 = *(const float4*)&wsl[r * 260 + ty * 16 + jj * 4];
        float4& A0 = acc4[jj * 4 + 0];
        float4& A1 = acc4[jj * 4 + 1];
        float4& A2 = acc4[jj * 4 + 2];
        float4& A3 = acc4[jj * 4 + 3];
        A0.x += w4.x * a4.x; A0.y += w4.x * a4.y; A0.z += w4.x * a4.z; A0.w += w4.x * a4.w;
        A1.x += w4.y * a4.x; A1.y += w4.y * a4.y; A1.z += w4.y * a4.z; A1.w += w4.y * a4.w;
        A2.x += w4.z * a4.x; A2.y += w4.z * a4.y; A2.z += w4.z * a4.z; A2.w += w4.z * a4.w;
        A3.x += w4.w * a4.x; A3.y += w4.w * a4.y; A3.z += w4.w * a4.z; A3.w += w4.w * a4.w;
      }
    }
    __syncthreads();
  }

  #pragma unroll
  for (int dd = 0; dd < 16; ++dd) {
    int d = ty * 16 + dd;
    float bv = bout[d];
    float4 o = acc4[dd];
    o.x += bv; o.y += bv; o.z += bv; o.w += bv;
    *(float4*)&O[(size_t)b * DIMC * NPIX + (size_t)d * NPIX + t0 + tx * 4] = o;
  }
}

extern "C" void kernel_launch(void* const* d_in, const int* in_sizes, int n_in,
                              void* d_out, int out_size, void* d_ws, size_t ws_size,
                              hipStream_t stream) {
  const float* x    = (const float*)d_in[0];
  const float* Wk   = (const float*)d_in[2];
  const float* Wv   = (const float*)d_in[3];
  const float* Wq   = (const float*)d_in[4];
  const float* Wout = (const float*)d_in[5];
  const float* bout = (const float*)d_in[6];
  float* out = (float*)d_out;

  float* Xk = (float*)d_ws;
  float* Xv = Xk + (size_t)4 * DIMC * NPIX;
  float* Xq = out;  // d_out doubles as Xq / attn-out scratch (window-exclusive)

  proj_kernel<<<dim3(225, 4, 12), 256, 0, stream>>>(x, Wk, Wv, Wq, Xq, Xk, Xv);
  attn_kernel<<<dim3(2304), 256, 0, stream>>>(Xq, Xk, Xv, Xq);
  outproj_kernel<<<dim3(225, 4), 256, 0, stream>>>(Xq, Wout, bout, out);
}

// Round 3
// 719.974 us; speedup vs baseline: 2.4256x; 2.4256x over previous
//
#include <hip/hip_runtime.h>

#define DIMC 256
#define NPIX 14400      // 120*120
#define IMGW 120
#define IMGH 120
#define XS   460800     // per (b,h) slice stride in elements = 14400*32

__device__ inline unsigned short f2bf(float f) {
  unsigned int x = __float_as_uint(f);
  unsigned int r = x + 0x7FFFu + ((x >> 16) & 1u);
  return (unsigned short)(r >> 16);
}
__device__ inline float bflo(unsigned int u) { return __uint_as_float(u << 16); }
__device__ inline float bfhi(unsigned int u) { return __uint_as_float(u & 0xFFFF0000u); }

// ---------------- K1: fused triple projection ----------------
// O_head_sliced[b][h][pix][32] = W @ x (per batch); Q -> f32 (d_out), K/V -> bf16 (ws)
// grid: (225 pix tiles of 64, 4 batches, 12 = mat*4 + dtile)
__global__ __launch_bounds__(256) void proj_kernel(
    const float* __restrict__ x,
    const float* __restrict__ Wk, const float* __restrict__ Wv,
    const float* __restrict__ Wq,
    float* __restrict__ XqT,
    unsigned short* __restrict__ XkT, unsigned short* __restrict__ XvT)
{
  __shared__ __align__(16) float sh[4352];  // xs[16*64] | wsl[16*68]; reused as trs[64*68]
  float* xs  = sh;
  float* wsl = sh + 1024;

  const int tb = blockIdx.x;
  const int b  = blockIdx.y;
  const int z  = blockIdx.z;
  const int mat = z >> 2, dt = z & 3;
  const int t0 = tb * 64, d0 = dt * 64;

  const float* W = (mat == 0) ? Wq : (mat == 1) ? Wk : Wv;
  const float sc = (mat == 0) ? 0.17677669529663687f : 1.0f;  // 32^-0.5 for Q

  const int tid = threadIdx.x;
  const int tx = tid & 15, ty = tid >> 4;

  float4 acc[4];
  #pragma unroll
  for (int j = 0; j < 4; ++j) acc[j] = make_float4(0.f, 0.f, 0.f, 0.f);

  const float* xb = x + (size_t)b * DIMC * NPIX + t0;

  for (int c0 = 0; c0 < 256; c0 += 16) {
    #pragma unroll
    for (int i = 0; i < 4; ++i) {
      int f = tid + 256 * i;
      int r = f >> 6, col = f & 63;
      xs[r * 64 + col] = xb[(size_t)(c0 + r) * NPIX + col];
    }
    #pragma unroll
    for (int i = 0; i < 4; ++i) {
      int f = tid + 256 * i;
      int j = f >> 4, chl = f & 15;
      wsl[chl * 68 + j] = W[(d0 + j) * 256 + c0 + chl];
    }
    __syncthreads();
    #pragma unroll
    for (int r = 0; r < 16; ++r) {
      float4 a4 = *(const float4*)&xs[r * 64 + tx * 4];
      float4 b4 = *(const float4*)&wsl[r * 68 + ty * 4];
      acc[0].x += b4.x * a4.x; acc[0].y += b4.x * a4.y; acc[0].z += b4.x * a4.z; acc[0].w += b4.x * a4.w;
      acc[1].x += b4.y * a4.x; acc[1].y += b4.y * a4.y; acc[1].z += b4.y * a4.z; acc[1].w += b4.y * a4.w;
      acc[2].x += b4.z * a4.x; acc[2].y += b4.z * a4.y; acc[2].z += b4.z * a4.z; acc[2].w += b4.z * a4.w;
      acc[3].x += b4.w * a4.x; acc[3].y += b4.w * a4.y; acc[3].z += b4.w * a4.z; acc[3].w += b4.w * a4.w;
    }
    __syncthreads();
  }

  // ---- transpose epilogue: sh[pix_local][d_local], then head-sliced writes ----
  float4 cv0 = make_float4(acc[0].x*sc, acc[1].x*sc, acc[2].x*sc, acc[3].x*sc);
  float4 cv1 = make_float4(acc[0].y*sc, acc[1].y*sc, acc[2].y*sc, acc[3].y*sc);
  float4 cv2 = make_float4(acc[0].z*sc, acc[1].z*sc, acc[2].z*sc, acc[3].z*sc);
  float4 cv3 = make_float4(acc[0].w*sc, acc[1].w*sc, acc[2].w*sc, acc[3].w*sc);
  *(float4*)&sh[(tx*4+0)*68 + ty*4] = cv0;
  *(float4*)&sh[(tx*4+1)*68 + ty*4] = cv1;
  *(float4*)&sh[(tx*4+2)*68 + ty*4] = cv2;
  *(float4*)&sh[(tx*4+3)*68 + ty*4] = cv3;
  __syncthreads();
  const int h0 = d0 >> 5;
  if (mat == 0) {
    #pragma unroll
    for (int it = 0; it < 4; ++it) {
      int f = tid + 256 * it;          // 0..1023: f = pixl*16 + hl*8 + dg
      int dg = f & 7, hl = (f >> 3) & 1, pixl = f >> 4;
      float4 v = *(float4*)&sh[pixl*68 + hl*32 + dg*4];
      *(float4*)&XqT[((size_t)(b*8 + h0 + hl) * NPIX + (t0 + pixl)) * 32 + dg*4] = v;
    }
  } else {
    unsigned short* O = (mat == 1) ? XkT : XvT;
    #pragma unroll
    for (int it = 0; it < 4; ++it) {
      int f = tid + 256 * it;
      int dg = f & 7, hl = (f >> 3) & 1, pixl = f >> 4;
      float4 v = *(float4*)&sh[pixl*68 + hl*32 + dg*4];
      ushort4 u;
      u.x = f2bf(v.x); u.y = f2bf(v.y); u.z = f2bf(v.z); u.w = f2bf(v.w);
      *(ushort4*)&O[((size_t)(b*8 + h0 + hl) * NPIX + (t0 + pixl)) * 32 + dg*4] = u;
    }
  }
}

// ---------------- K2: fused window attention, 1 wave per (window, head) ----------------
// grid: 18432 = head*2304 + (b*576 + by*24 + bx); block: 64 threads
__global__ __launch_bounds__(64) void attn_kernel(
    const float* __restrict__ XqT,            // f32, in d_out (read-only here)
    const unsigned short* __restrict__ XkT,   // bf16, ws
    const unsigned short* __restrict__ XvT,   // bf16, ws
    float* __restrict__ AO)                   // f32, ws
{
  __shared__ __align__(16) float qs[800];       // [q][32]
  __shared__ __align__(16) float SA[25 * 52];   // S then A, [q][52]
  __shared__ __align__(16) float vs[49 * 40];   // [pp][40]
  __shared__ __align__(16) float cb[2 * 25 * 13]; // [half][kp][13]

  const int lane = threadIdx.x;
  const int bid = blockIdx.x;
  const int h = bid / 2304;
  const int w = bid % 2304;
  const int b = w / 576;
  const int rr = w % 576;
  const int by = rr / 24, bx = rr % 24;
  const int y0 = by * 5, x0 = bx * 5;
  const size_t sbase = (size_t)(b * 8 + h) * XS;
  const float* Qg = XqT + sbase;
  const unsigned short* Kg = XkT + sbase;
  const unsigned short* Vg = XvT + sbase;

  // --- load Q window (25 pix x 32 f32) coalesced: rows of 40 contiguous float4 ---
  #pragma unroll
  for (int it = 0; it < 4; ++it) {
    int f4 = lane + 64 * it;
    if (f4 < 200) {
      int wy = f4 / 40, t = f4 % 40;
      float4 v = *((const float4*)(Qg + ((size_t)((y0 + wy) * IMGW + x0)) * 32) + t);
      *((float4*)&qs[wy * 160] + t) = v;
    }
  }

  // --- load K halo row into registers (lane = halo pixel, 49 active), bf16 -> f32 ---
  float kreg[32];
  {
    int hy = lane / 7, hx = lane % 7;
    int gy = y0 - 1 + hy, gx = x0 - 1 + hx;
    bool inb = (lane < 49) && gy >= 0 && gy < IMGH && gx >= 0 && gx < IMGW;
    const uint4* kp4 = (const uint4*)(Kg + (size_t)(inb ? (gy * IMGW + gx) : 0) * 32);
    #pragma unroll
    for (int j = 0; j < 4; ++j) {
      uint4 u = inb ? kp4[j] : make_uint4(0u, 0u, 0u, 0u);
      kreg[j*8+0] = bflo(u.x); kreg[j*8+1] = bfhi(u.x);
      kreg[j*8+2] = bflo(u.y); kreg[j*8+3] = bfhi(u.y);
      kreg[j*8+4] = bflo(u.z); kreg[j*8+5] = bfhi(u.z);
      kreg[j*8+6] = bflo(u.w); kreg[j*8+7] = bfhi(u.w);
    }
  }

  // --- load V halo into LDS vs[pp][40] (f32), bf16 -> f32 ---
  #pragma unroll
  for (int it = 0; it < 7; ++it) {
    int f4 = lane + 64 * it;
    if (f4 < 392) {
      int pp = f4 >> 3, dg = f4 & 7;
      int hy = pp / 7, hx = pp % 7;
      int gy = y0 - 1 + hy, gx = x0 - 1 + hx;
      float4 v = make_float4(0.f, 0.f, 0.f, 0.f);
      if (gy >= 0 && gy < IMGH && gx >= 0 && gx < IMGW) {
        uint2 u = *((const uint2*)(Vg + (size_t)(gy * IMGW + gx) * 32) + dg);
        v = make_float4(bflo(u.x), bfhi(u.x), bflo(u.y), bfhi(u.y));
      }
      *(float4*)&vs[pp * 40 + dg * 4] = v;
    }
  }
  __syncthreads();

  // --- QK^T: S[q][pp] = Q[q] . K[pp], K in regs, Q broadcast from LDS ---
  #pragma unroll 2
  for (int q = 0; q < 25; ++q) {
    const float4* qr = (const float4*)&qs[q * 32];
    float acc = 0.f;
    #pragma unroll
    for (int j = 0; j < 8; ++j) {
      float4 a = qr[j];
      acc += a.x * kreg[j*4+0] + a.y * kreg[j*4+1] + a.z * kreg[j*4+2] + a.w * kreg[j*4+3];
    }
    if (lane < 49) SA[q * 52 + lane] = acc;
  }
  __syncthreads();

  // --- expand -> softmax -> fold, two q rows per iteration (lane halves) ---
  const float NEG = -0.5f, DPN = 11.f/6.f, NORc = -0.375f;
  for (int t = 0; t < 13; ++t) {
    const int half = lane >> 5, kpl = lane & 31;
    const int q = 2 * t + half;
    const bool act = (kpl < 25) && (q < 25);
    float l[9];
    float m = -1e30f;
    if (act) {
      int ky = kpl / 5, kx = kpl % 5;
      float s9[9];
      #pragma unroll
      for (int dy = 0; dy < 3; ++dy)
        #pragma unroll
        for (int dx = 0; dx < 3; ++dx)
          s9[dy*3+dx] = SA[q * 52 + (ky + dy) * 7 + (kx + dx)];
      float st = ((s9[0]+s9[1]) + (s9[2]+s9[3])) + ((s9[5]+s9[6]) + (s9[7]+s9[8])) + s9[4];
      l[0] = NORc * st + 4.375f * s9[4];
      float base = NEG * st + DPN * s9[4];
      l[1] = base + DPN * (s9[1] + s9[7]);
      l[2] = base + DPN * (s9[3] + s9[5]);
      l[3] = base + DPN * (s9[0] + s9[8]);
      l[4] = base + DPN * (s9[2] + s9[6]);
      l[5] = base + DPN * (s9[1] + s9[3]);
      l[6] = base + DPN * (s9[1] + s9[5]);
      l[7] = base + DPN * (s9[3] + s9[7]);
      l[8] = base + DPN * (s9[5] + s9[7]);
      #pragma unroll
      for (int i = 0; i < 9; ++i) m = fmaxf(m, l[i]);
    }
    #pragma unroll
    for (int o = 16; o >= 1; o >>= 1) m = fmaxf(m, __shfl_xor(m, o));
    float p[9]; float psum = 0.f;
    if (act) {
      #pragma unroll
      for (int i = 0; i < 9; ++i) { p[i] = __expf(l[i] - m); psum += p[i]; }
    }
    float s = act ? psum : 0.f;
    #pragma unroll
    for (int o = 16; o >= 1; o >>= 1) s += __shfl_xor(s, o);
    float rinv = 1.f / s;
    if (act) {
      float psm0  = psum - p[0];
      float basec = NEG * psm0 + NORc * p[0];
      float c[9];
      c[0] = basec + DPN * p[3];
      c[1] = basec + DPN * ((p[1] + p[5]) + p[6]);
      c[2] = basec + DPN * p[4];
      c[3] = basec + DPN * ((p[2] + p[5]) + p[7]);
      c[4] = 4.f * p[0] + (4.f/3.f) * psm0;
      c[5] = basec + DPN * ((p[2] + p[6]) + p[8]);
      c[6] = basec + DPN * p[4];
      c[7] = basec + DPN * ((p[1] + p[7]) + p[8]);
      c[8] = basec + DPN * p[3];
      float* cw = &cb[(half * 25 + kpl) * 13];
      #pragma unroll
      for (int i = 0; i < 9; ++i) cw[i] = c[i] * rinv;
    }
    __syncthreads();
    // gather: A[q][halo] = sum of valid c contributions (overwrites consumed S rows)
    #pragma unroll
    for (int pass = 0; pass < 2; ++pass) {
      int qg = 2 * t + pass;
      if (qg < 25 && lane < 49) {
        int hy = lane / 7, hx = lane % 7;
        float a = 0.f;
        #pragma unroll
        for (int dy = 0; dy < 3; ++dy) {
          int ky = hy - dy;
          if ((unsigned)ky < 5u) {
            #pragma unroll
            for (int dx = 0; dx < 3; ++dx) {
              int kx = hx - dx;
              if ((unsigned)kx < 5u)
                a += cb[(pass * 25 + ky * 5 + kx) * 13 + dy * 3 + dx];
            }
          }
        }
        SA[qg * 52 + lane] = a;
      }
    }
    __syncthreads();
  }

  // --- PV: out[q][d] = sum_pp A[q][pp] * V[pp][d]; lane = (q, dhalf) ---
  if (lane < 50) {
    const int q = lane >> 1, dh = lane & 1;
    float4 a0 = make_float4(0,0,0,0), a1 = a0, a2 = a0, a3 = a0;
    for (int pp = 0; pp < 49; ++pp) {
      float a = SA[q * 52 + pp];
      const float4* vr = (const float4*)&vs[pp * 40 + dh * 16];
      float4 v0 = vr[0], v1 = vr[1], v2 = vr[2], v3 = vr[3];
      a0.x += a*v0.x; a0.y += a*v0.y; a0.z += a*v0.z; a0.w += a*v0.w;
      a1.x += a*v1.x; a1.y += a*v1.y; a1.z += a*v1.z; a1.w += a*v1.w;
      a2.x += a*v2.x; a2.y += a*v2.y; a2.z += a*v2.z; a2.w += a*v2.w;
      a3.x += a*v3.x; a3.y += a*v3.y; a3.z += a*v3.z; a3.w += a*v3.w;
    }
    float4* dst = (float4*)(AO + sbase +
        ((size_t)((y0 + q / 5) * IMGW + x0 + q % 5)) * 32 + dh * 16);
    dst[0] = a0; dst[1] = a1; dst[2] = a2; dst[3] = a3;
  }
}

// ---------------- K3: output projection ----------------
// O[b][d][pix] = sum_c Wout[d][c]*AO[b][h(c)][pix][dl(c)] + bout[d]
__global__ __launch_bounds__(256) void outproj_kernel(
    const float* __restrict__ AO, const float* __restrict__ Wout,
    const float* __restrict__ bout, float* __restrict__ O)
{
  const int tb = blockIdx.x, b = blockIdx.y;
  const int t0 = tb * 64;
  __shared__ __align__(16) float as[16 * 68];
  __shared__ __align__(16) float wsl[16 * 260];
  const int tid = threadIdx.x;
  const int tx = tid & 15, ty = tid >> 4;

  float4 acc4[16];
  #pragma unroll
  for (int j = 0; j < 16; ++j) acc4[j] = make_float4(0.f, 0.f, 0.f, 0.f);

  for (int c0 = 0; c0 < 256; c0 += 16) {
    const float* ab = AO + (size_t)(b * 8 + (c0 >> 5)) * XS + (size_t)t0 * 32 + (c0 & 31);
    #pragma unroll
    for (int i = 0; i < 4; ++i) {
      int f = tid + 256 * i;
      int cl = f & 15, pixl = f >> 4;
      as[cl * 68 + pixl] = ab[(size_t)pixl * 32 + cl];
    }
    #pragma unroll
    for (int i = 0; i < 16; ++i) {
      int f = tid + 256 * i;
      int d = f >> 4, r = f & 15;
      wsl[r * 260 + d] = Wout[d * 256 + c0 + r];
    }
    __syncthreads();
    #pragma unroll
    for (int r = 0; r < 16; ++r) {
      float4 a4 = *(const float4*)&as[r * 68 + tx * 4];
      #pragma unroll
      for (int jj = 0; jj < 4; ++jj) {
        float4 w4 = *(const float4*)&wsl[r * 260 + ty * 16 + jj * 4];
        float4& A0 = acc4[jj * 4 + 0];
        float4& A1 = acc4[jj * 4 + 1];
        float4& A2 = acc4[jj * 4 + 2];
        float4& A3 = acc4[jj * 4 + 3];
        A0.x += w4.x * a4.x; A0.y += w4.x * a4.y; A0.z += w4.x * a4.z; A0.w += w4.x * a4.w;
        A1.x += w4.y * a4.x; A1.y += w4.y * a4.y; A1.z += w4.y * a4.z; A1.w += w4.y * a4.w;
        A2.x += w4.z * a4.x; A2.y += w4.z * a4.y; A2.z += w4.z * a4.z; A2.w += w4.z * a4.w;
        A3.x += w4.w * a4.x; A3.y += w4.w * a4.y; A3.z += w4.w * a4.z; A3.w += w4.w * a4.w;
      }
    }
    __syncthreads();
  }

  #pragma unroll
  for (int dd = 0; dd < 16; ++dd) {
    int d = ty * 16 + dd;
    float bv = bout[d];
    float4 o = acc4[dd];
    o.x += bv; o.y += bv; o.z += bv; o.w += bv;
    *(float4*)&O[(size_t)b * DIMC * NPIX + (size_t)d * NPIX + t0 + tx * 4] = o;
  }
}

extern "C" void kernel_launch(void* const* d_in, const int* in_sizes, int n_in,
                              void* d_out, int out_size, void* d_ws, size_t ws_size,
                              hipStream_t stream) {
  const float* x    = (const float*)d_in[0];
  const float* Wk   = (const float*)d_in[2];
  const float* Wv   = (const float*)d_in[3];
  const float* Wq   = (const float*)d_in[4];
  const float* Wout = (const float*)d_in[5];
  const float* bout = (const float*)d_in[6];

  // ws layout: XkT bf16 | XvT bf16 | AO f32  == 117,964,800 B total (same as R1's proven usage)
  unsigned short* XkT = (unsigned short*)d_ws;
  unsigned short* XvT = XkT + (size_t)32 * NPIX * 32;          // 4*8*14400*32 ushorts
  float*          AO  = (float*)(XvT + (size_t)32 * NPIX * 32);
  float*          XqT = (float*)d_out;  // Q lives in d_out; only read by attn, rewritten by outproj later

  proj_kernel<<<dim3(225, 4, 12), 256, 0, stream>>>(x, Wk, Wv, Wq, XqT, XkT, XvT);
  attn_kernel<<<dim3(18432), 64, 0, stream>>>(XqT, XkT, XvT, AO);
  outproj_kernel<<<dim3(225, 4), 256, 0, stream>>>(AO, Wout, bout, (float*)d_out);
}

// Round 4
// 401.545 us; speedup vs baseline: 4.3492x; 1.7930x over previous
//
#include <hip/hip_runtime.h>

#define IMGW 120
#define IMGH 120
#define NPIX 14400      // 120*120
#define XS   460800     // per (b,h) slice stride in elements = 14400*32

typedef unsigned short u16;
typedef short bf16x8 __attribute__((ext_vector_type(8)));
typedef float f32x4 __attribute__((ext_vector_type(4)));

__device__ inline u16 f2bf(float f) {
  unsigned int x = __float_as_uint(f);
  unsigned int r = x + 0x7FFFu + ((x >> 16) & 1u);
  return (u16)(r >> 16);
}
__device__ inline unsigned int pk2(float a, float b) {
  return (unsigned int)f2bf(a) | ((unsigned int)f2bf(b) << 16);
}
__device__ inline float bflo(unsigned int u) { return __uint_as_float(u << 16); }
__device__ inline float bfhi(unsigned int u) { return __uint_as_float(u & 0xFFFF0000u); }

// ---------------- P1: weight convert f32 -> bf16 (Wq pre-scaled by 32^-0.5) ----------------
__global__ __launch_bounds__(256) void wconv_kernel(
    const float* __restrict__ Wq, const float* __restrict__ Wk,
    const float* __restrict__ Wv, const float* __restrict__ Wo,
    u16* __restrict__ Wb)
{
  const int t = threadIdx.x, bx = blockIdx.x, mat = blockIdx.y;
  const float* src = mat == 0 ? Wq : mat == 1 ? Wk : mat == 2 ? Wv : Wo;
  const float sc = (mat == 0) ? 0.17677669529663687f : 1.0f;
  const int e0 = (bx * 256 + t) * 4;
  float4 v = *(const float4*)(src + e0);
  uint2 u;
  u.x = pk2(v.x * sc, v.y * sc);
  u.y = pk2(v.z * sc, v.w * sc);
  *(uint2*)(Wb + (size_t)mat * 65536 + e0) = u;
}

// ---------------- P2: transpose-convert x [b][ch][pix] f32 -> x_t [b][pix][256] bf16 ----------------
__global__ __launch_bounds__(256) void xpose_kernel(
    const float* __restrict__ x, u16* __restrict__ x_t)
{
  __shared__ u16 sh[64 * 66];
  const int t = threadIdx.x;
  const int p0 = blockIdx.x * 64;
  const int b  = blockIdx.y;
  const int c0 = blockIdx.z * 64;
  const float* xb = x + ((size_t)b * 256 + c0) * NPIX + p0;
  #pragma unroll
  for (int it = 0; it < 16; ++it) {
    int ch = it * 4 + (t >> 6), pix = t & 63;
    sh[pix * 66 + ch] = f2bf(xb[(size_t)ch * NPIX + pix]);
  }
  __syncthreads();
  u16* ob = x_t + ((size_t)b * NPIX + p0) * 256 + c0;
  const unsigned int* sh32 = (const unsigned int*)sh;
  #pragma unroll
  for (int it = 0; it < 8; ++it) {
    int flat = it * 256 + t;
    int pix = flat >> 5, c2 = flat & 31;
    ((unsigned int*)(ob + (size_t)pix * 256))[c2] = sh32[pix * 33 + c2];
  }
}

// ---------------- K1: triple projection via MFMA ----------------
// D[dim][pix] = W[dim][ch] . x_t[pix][ch]; out head-sliced bf16 [b*8+h][pix][32]
// grid: (225 pix tiles of 64, 4 batch, 3 mat), 256 thr = 4 waves
__global__ __launch_bounds__(256) void projmm_kernel(
    const u16* __restrict__ x_t, const u16* __restrict__ Wb,
    u16* __restrict__ Qb, u16* __restrict__ Kb, u16* __restrict__ Vb)
{
  __shared__ u16 Ws[256 * 40];   // [dim][32+pad] bf16, row stride 80B
  __shared__ u16 Xs[64 * 40];    // [pix][32+pad]
  const int t = threadIdx.x;
  const int lane = t & 63, wv = t >> 6;
  const int p0 = blockIdx.x * 64;
  const int b  = blockIdx.y;
  const int mat = blockIdx.z;

  const u16* Wm = Wb + (size_t)mat * 65536;
  const u16* Xb = x_t + ((size_t)b * NPIX + p0) * 256;

  f32x4 acc[4][4];
  #pragma unroll
  for (int i = 0; i < 4; ++i)
    #pragma unroll
    for (int j = 0; j < 4; ++j) acc[i][j] = {0.f, 0.f, 0.f, 0.f};

  for (int kk = 0; kk < 8; ++kk) {
    #pragma unroll
    for (int p = 0; p < 4; ++p) {          // W tile [256][32]
      int fl = t + 256 * p;
      int d = fl >> 2, c = fl & 3;
      uint4 u = *(const uint4*)(Wm + d * 256 + kk * 32 + c * 8);
      *(uint4*)&Ws[d * 40 + c * 8] = u;
    }
    {                                       // X tile [64][32]
      int pix = t >> 2, c = t & 3;
      uint4 u = *(const uint4*)(Xb + (size_t)pix * 256 + kk * 32 + c * 8);
      *(uint4*)&Xs[pix * 40 + c * 8] = u;
    }
    __syncthreads();
    bf16x8 af[4], bfr[4];
    #pragma unroll
    for (int f = 0; f < 4; ++f)
      af[f] = *(const bf16x8*)&Ws[(wv * 64 + f * 16 + (lane & 15)) * 40 + (lane >> 4) * 8];
    #pragma unroll
    for (int f = 0; f < 4; ++f)
      bfr[f] = *(const bf16x8*)&Xs[(f * 16 + (lane & 15)) * 40 + (lane >> 4) * 8];
    #pragma unroll
    for (int df = 0; df < 4; ++df)
      #pragma unroll
      for (int pf = 0; pf < 4; ++pf)
        acc[df][pf] = __builtin_amdgcn_mfma_f32_16x16x32_bf16(af[df], bfr[pf], acc[df][pf], 0, 0, 0);
    __syncthreads();
  }

  u16* O = (mat == 0) ? Qb : (mat == 1) ? Kb : Vb;
  #pragma unroll
  for (int df = 0; df < 4; ++df) {
    int dim0 = wv * 64 + df * 16 + (lane >> 4) * 4;   // 4 consecutive dims per lane
    int h = dim0 >> 5, dl0 = dim0 & 31;
    #pragma unroll
    for (int pf = 0; pf < 4; ++pf) {
      int pix = p0 + pf * 16 + (lane & 15);
      f32x4 v = acc[df][pf];
      uint2 u;
      u.x = pk2(v[0], v[1]);
      u.y = pk2(v[2], v[3]);
      *(uint2*)&O[((size_t)(b * 8 + h) * NPIX + pix) * 32 + dl0] = u;
    }
  }
}

// ---------------- K2: fused window attention, 1 wave per (window, head) ----------------
__global__ __launch_bounds__(64) void attn_kernel(
    const u16* __restrict__ Qb,   // bf16 [b8h][pix][32]
    const u16* __restrict__ Kb,
    const u16* __restrict__ Vb,
    u16* __restrict__ AO)         // bf16 [b8h][pix][32]
{
  __shared__ __align__(16) float qs[800];         // [q][32]
  __shared__ __align__(16) float SA[25 * 52];     // S then A
  __shared__ __align__(16) float vs[49 * 40];     // [pp][40]
  __shared__ __align__(16) float cb[2 * 25 * 13];

  const int lane = threadIdx.x;
  const int bid = blockIdx.x;
  const int h = bid / 2304;
  const int w = bid % 2304;
  const int b = w / 576;
  const int rr = w % 576;
  const int by = rr / 24, bx = rr % 24;
  const int y0 = by * 5, x0 = bx * 5;
  const size_t sbase = (size_t)(b * 8 + h) * XS;
  const u16* Qg = Qb + sbase;
  const u16* Kg = Kb + sbase;
  const u16* Vg = Vb + sbase;

  // --- load Q window (25 pix x 32) bf16 -> f32 LDS ---
  #pragma unroll
  for (int it = 0; it < 2; ++it) {
    int idx = lane + 64 * it;
    if (idx < 100) {
      int pixw = idx >> 2, c = idx & 3;
      int wy = pixw / 5, wx = pixw % 5;
      uint4 u = *(const uint4*)(Qg + ((size_t)((y0 + wy) * IMGW + x0 + wx)) * 32 + c * 8);
      float* qd = &qs[pixw * 32 + c * 8];
      qd[0] = bflo(u.x); qd[1] = bfhi(u.x); qd[2] = bflo(u.y); qd[3] = bfhi(u.y);
      qd[4] = bflo(u.z); qd[5] = bfhi(u.z); qd[6] = bflo(u.w); qd[7] = bfhi(u.w);
    }
  }

  // --- K halo into registers (lane = halo pixel) ---
  float kreg[32];
  {
    int hy = lane / 7, hx = lane % 7;
    int gy = y0 - 1 + hy, gx = x0 - 1 + hx;
    bool inb = (lane < 49) && gy >= 0 && gy < IMGH && gx >= 0 && gx < IMGW;
    const uint4* kp4 = (const uint4*)(Kg + (size_t)(inb ? (gy * IMGW + gx) : 0) * 32);
    #pragma unroll
    for (int j = 0; j < 4; ++j) {
      uint4 u = inb ? kp4[j] : make_uint4(0u, 0u, 0u, 0u);
      kreg[j*8+0] = bflo(u.x); kreg[j*8+1] = bfhi(u.x);
      kreg[j*8+2] = bflo(u.y); kreg[j*8+3] = bfhi(u.y);
      kreg[j*8+4] = bflo(u.z); kreg[j*8+5] = bfhi(u.z);
      kreg[j*8+6] = bflo(u.w); kreg[j*8+7] = bfhi(u.w);
    }
  }

  // --- V halo into LDS vs[pp][40] f32 ---
  #pragma unroll
  for (int it = 0; it < 7; ++it) {
    int f4 = lane + 64 * it;
    if (f4 < 392) {
      int pp = f4 >> 3, dg = f4 & 7;
      int hy = pp / 7, hx = pp % 7;
      int gy = y0 - 1 + hy, gx = x0 - 1 + hx;
      float4 v = make_float4(0.f, 0.f, 0.f, 0.f);
      if (gy >= 0 && gy < IMGH && gx >= 0 && gx < IMGW) {
        uint2 u = *((const uint2*)(Vg + (size_t)(gy * IMGW + gx) * 32) + dg);
        v = make_float4(bflo(u.x), bfhi(u.x), bflo(u.y), bfhi(u.y));
      }
      *(float4*)&vs[pp * 40 + dg * 4] = v;
    }
  }
  __syncthreads();

  // --- QK^T ---
  #pragma unroll 2
  for (int q = 0; q < 25; ++q) {
    const float4* qr = (const float4*)&qs[q * 32];
    float acc = 0.f;
    #pragma unroll
    for (int j = 0; j < 8; ++j) {
      float4 a = qr[j];
      acc += a.x * kreg[j*4+0] + a.y * kreg[j*4+1] + a.z * kreg[j*4+2] + a.w * kreg[j*4+3];
    }
    if (lane < 49) SA[q * 52 + lane] = acc;
  }
  __syncthreads();

  // --- expand -> softmax -> fold ---
  const float NEG = -0.5f, DPN = 11.f/6.f, NORc = -0.375f;
  for (int t = 0; t < 13; ++t) {
    const int half = lane >> 5, kpl = lane & 31;
    const int q = 2 * t + half;
    const bool act = (kpl < 25) && (q < 25);
    float l[9];
    float m = -1e30f;
    if (act) {
      int ky = kpl / 5, kx = kpl % 5;
      float s9[9];
      #pragma unroll
      for (int dy = 0; dy < 3; ++dy)
        #pragma unroll
        for (int dx = 0; dx < 3; ++dx)
          s9[dy*3+dx] = SA[q * 52 + (ky + dy) * 7 + (kx + dx)];
      float st = ((s9[0]+s9[1]) + (s9[2]+s9[3])) + ((s9[5]+s9[6]) + (s9[7]+s9[8])) + s9[4];
      l[0] = NORc * st + 4.375f * s9[4];
      float base = NEG * st + DPN * s9[4];
      l[1] = base + DPN * (s9[1] + s9[7]);
      l[2] = base + DPN * (s9[3] + s9[5]);
      l[3] = base + DPN * (s9[0] + s9[8]);
      l[4] = base + DPN * (s9[2] + s9[6]);
      l[5] = base + DPN * (s9[1] + s9[3]);
      l[6] = base + DPN * (s9[1] + s9[5]);
      l[7] = base + DPN * (s9[3] + s9[7]);
      l[8] = base + DPN * (s9[5] + s9[7]);
      #pragma unroll
      for (int i = 0; i < 9; ++i) m = fmaxf(m, l[i]);
    }
    #pragma unroll
    for (int o = 16; o >= 1; o >>= 1) m = fmaxf(m, __shfl_xor(m, o));
    float p[9]; float psum = 0.f;
    if (act) {
      #pragma unroll
      for (int i = 0; i < 9; ++i) { p[i] = __expf(l[i] - m); psum += p[i]; }
    }
    float s = act ? psum : 0.f;
    #pragma unroll
    for (int o = 16; o >= 1; o >>= 1) s += __shfl_xor(s, o);
    float rinv = 1.f / s;
    if (act) {
      float psm0  = psum - p[0];
      float basec = NEG * psm0 + NORc * p[0];
      float c[9];
      c[0] = basec + DPN * p[3];
      c[1] = basec + DPN * ((p[1] + p[5]) + p[6]);
      c[2] = basec + DPN * p[4];
      c[3] = basec + DPN * ((p[2] + p[5]) + p[7]);
      c[4] = 4.f * p[0] + (4.f/3.f) * psm0;
      c[5] = basec + DPN * ((p[2] + p[6]) + p[8]);
      c[6] = basec + DPN * p[4];
      c[7] = basec + DPN * ((p[1] + p[7]) + p[8]);
      c[8] = basec + DPN * p[3];
      float* cw = &cb[(half * 25 + kpl) * 13];
      #pragma unroll
      for (int i = 0; i < 9; ++i) cw[i] = c[i] * rinv;
    }
    __syncthreads();
    #pragma unroll
    for (int pass = 0; pass < 2; ++pass) {
      int qg = 2 * t + pass;
      if (qg < 25 && lane < 49) {
        int hy = lane / 7, hx = lane % 7;
        float a = 0.f;
        #pragma unroll
        for (int dy = 0; dy < 3; ++dy) {
          int ky = hy - dy;
          if ((unsigned)ky < 5u) {
            #pragma unroll
            for (int dx = 0; dx < 3; ++dx) {
              int kx = hx - dx;
              if ((unsigned)kx < 5u)
                a += cb[(pass * 25 + ky * 5 + kx) * 13 + dy * 3 + dx];
            }
          }
        }
        SA[qg * 52 + lane] = a;
      }
    }
    __syncthreads();
  }

  // --- PV, write AO bf16 ---
  if (lane < 50) {
    const int q = lane >> 1, dh = lane & 1;
    float4 a0 = make_float4(0,0,0,0), a1 = a0, a2 = a0, a3 = a0;
    for (int pp = 0; pp < 49; ++pp) {
      float a = SA[q * 52 + pp];
      const float4* vr = (const float4*)&vs[pp * 40 + dh * 16];
      float4 v0 = vr[0], v1 = vr[1], v2 = vr[2], v3 = vr[3];
      a0.x += a*v0.x; a0.y += a*v0.y; a0.z += a*v0.z; a0.w += a*v0.w;
      a1.x += a*v1.x; a1.y += a*v1.y; a1.z += a*v1.z; a1.w += a*v1.w;
      a2.x += a*v2.x; a2.y += a*v2.y; a2.z += a*v2.z; a2.w += a*v2.w;
      a3.x += a*v3.x; a3.y += a*v3.y; a3.z += a*v3.z; a3.w += a*v3.w;
    }
    u16* dst = AO + sbase + ((size_t)((y0 + q / 5) * IMGW + x0 + q % 5)) * 32 + dh * 16;
    uint4 u0, u1;
    u0.x = pk2(a0.x, a0.y); u0.y = pk2(a0.z, a0.w);
    u0.z = pk2(a1.x, a1.y); u0.w = pk2(a1.z, a1.w);
    u1.x = pk2(a2.x, a2.y); u1.y = pk2(a2.z, a2.w);
    u1.z = pk2(a3.x, a3.y); u1.w = pk2(a3.z, a3.w);
    *(uint4*)dst = u0;
    *(uint4*)(dst + 8) = u1;
  }
}

// ---------------- K3: output projection via MFMA ----------------
// O[b][dim][pix] = Wout[dim][c] . AO[b][h(c)][pix][dl(c)] + bout[dim]
// grid: (225, 4), 256 thr = 4 waves; K-step kk = head
__global__ __launch_bounds__(256) void outmm_kernel(
    const u16* __restrict__ AOb, const u16* __restrict__ Wb,
    const float* __restrict__ bout, float* __restrict__ O)
{
  __shared__ u16 Ws[256 * 40];
  __shared__ u16 Xs[64 * 40];
  const int t = threadIdx.x;
  const int lane = t & 63, wv = t >> 6;
  const int p0 = blockIdx.x * 64;
  const int b  = blockIdx.y;
  const u16* Wm = Wb + (size_t)3 * 65536;

  f32x4 acc[4][4];
  #pragma unroll
  for (int i = 0; i < 4; ++i)
    #pragma unroll
    for (int j = 0; j < 4; ++j) acc[i][j] = {0.f, 0.f, 0.f, 0.f};

  for (int kk = 0; kk < 8; ++kk) {
    #pragma unroll
    for (int p = 0; p < 4; ++p) {
      int fl = t + 256 * p;
      int d = fl >> 2, c = fl & 3;
      uint4 u = *(const uint4*)(Wm + d * 256 + kk * 32 + c * 8);
      *(uint4*)&Ws[d * 40 + c * 8] = u;
    }
    {
      int pix = t >> 2, c = t & 3;
      uint4 u = *(const uint4*)(AOb + ((size_t)(b * 8 + kk) * NPIX + p0 + pix) * 32 + c * 8);
      *(uint4*)&Xs[pix * 40 + c * 8] = u;
    }
    __syncthreads();
    bf16x8 af[4], bfr[4];
    #pragma unroll
    for (int f = 0; f < 4; ++f)
      af[f] = *(const bf16x8*)&Ws[(wv * 64 + f * 16 + (lane & 15)) * 40 + (lane >> 4) * 8];
    #pragma unroll
    for (int f = 0; f < 4; ++f)
      bfr[f] = *(const bf16x8*)&Xs[(f * 16 + (lane & 15)) * 40 + (lane >> 4) * 8];
    #pragma unroll
    for (int df = 0; df < 4; ++df)
      #pragma unroll
      for (int pf = 0; pf < 4; ++pf)
        acc[df][pf] = __builtin_amdgcn_mfma_f32_16x16x32_bf16(af[df], bfr[pf], acc[df][pf], 0, 0, 0);
    __syncthreads();
  }

  #pragma unroll
  for (int df = 0; df < 4; ++df) {
    int dim0 = wv * 64 + df * 16 + (lane >> 4) * 4;
    float4 bv = *(const float4*)&bout[dim0];
    #pragma unroll
    for (int pf = 0; pf < 4; ++pf) {
      int pix = p0 + pf * 16 + (lane & 15);
      f32x4 v = acc[df][pf];
      float* ob = O + (size_t)b * 256 * NPIX + pix;
      ob[(size_t)(dim0 + 0) * NPIX] = v[0] + bv.x;
      ob[(size_t)(dim0 + 1) * NPIX] = v[1] + bv.y;
      ob[(size_t)(dim0 + 2) * NPIX] = v[2] + bv.z;
      ob[(size_t)(dim0 + 3) * NPIX] = v[3] + bv.w;
    }
  }
}

extern "C" void kernel_launch(void* const* d_in, const int* in_sizes, int n_in,
                              void* d_out, int out_size, void* d_ws, size_t ws_size,
                              hipStream_t stream) {
  const float* x    = (const float*)d_in[0];
  const float* Wk   = (const float*)d_in[2];
  const float* Wv   = (const float*)d_in[3];
  const float* Wq   = (const float*)d_in[4];
  const float* Wout = (const float*)d_in[5];
  const float* bout = (const float*)d_in[6];

  // d_out (58,982,400 B): x_t bf16 (29,491,200) | Qb bf16 (29,491,200) — exact fit
  u16* x_t = (u16*)d_out;
  u16* Qb  = x_t + (size_t)4 * NPIX * 256;
  // ws: Kb | Vb | AOb (bf16, 29,491,200 B each) | Wb (4x128KB) = 88.9 MB < 117.9 MB proven
  u16* Kb  = (u16*)d_ws;
  u16* Vb  = Kb + (size_t)4 * NPIX * 256;
  u16* AOb = Vb + (size_t)4 * NPIX * 256;
  u16* Wb  = AOb + (size_t)4 * NPIX * 256;

  wconv_kernel<<<dim3(64, 4), 256, 0, stream>>>(Wq, Wk, Wv, Wout, Wb);
  xpose_kernel<<<dim3(225, 4, 4), 256, 0, stream>>>(x, x_t);
  projmm_kernel<<<dim3(225, 4, 3), 256, 0, stream>>>(x_t, Wb, Qb, Kb, Vb);
  attn_kernel<<<dim3(18432), 64, 0, stream>>>(Qb, Kb, Vb, AOb);
  outmm_kernel<<<dim3(225, 4), 256, 0, stream>>>(AOb, Wb, bout, (float*)d_out);
}

// Round 6
// 381.843 us; speedup vs baseline: 4.5736x; 1.0516x over previous
//
#include <hip/hip_runtime.h>

#define IMGW 120
#define IMGH 120
#define NPIX 14400      // 120*120
#define XS   460800     // per (b,h) slice stride in elements = 14400*32

typedef unsigned short u16;
typedef short bf16x8 __attribute__((ext_vector_type(8)));
typedef float f32x4 __attribute__((ext_vector_type(4)));

__device__ inline u16 f2bf(float f) {
  unsigned int x = __float_as_uint(f);
  unsigned int r = x + 0x7FFFu + ((x >> 16) & 1u);
  return (u16)(r >> 16);
}
__device__ inline unsigned int pk2(float a, float b) {
  return (unsigned int)f2bf(a) | ((unsigned int)f2bf(b) << 16);
}
__device__ inline float bf2f(u16 h) { return __uint_as_float(((unsigned int)h) << 16); }

// ---------------- P1: weight convert f32 -> bf16 (Wq pre-scaled by 32^-0.5) ----------------
__global__ __launch_bounds__(256) void wconv_kernel(
    const float* __restrict__ Wq, const float* __restrict__ Wk,
    const float* __restrict__ Wv, const float* __restrict__ Wo,
    u16* __restrict__ Wb)
{
  const int t = threadIdx.x, bx = blockIdx.x, mat = blockIdx.y;
  const float* src = mat == 0 ? Wq : mat == 1 ? Wk : mat == 2 ? Wv : Wo;
  const float sc = (mat == 0) ? 0.17677669529663687f : 1.0f;
  const int e0 = (bx * 256 + t) * 4;
  float4 v = *(const float4*)(src + e0);
  uint2 u;
  u.x = pk2(v.x * sc, v.y * sc);
  u.y = pk2(v.z * sc, v.w * sc);
  *(uint2*)(Wb + (size_t)mat * 65536 + e0) = u;
}

// ---------------- P2: transpose-convert x [b][ch][pix] f32 -> x_t [b][pix][256] bf16 ----------------
__global__ __launch_bounds__(256) void xpose_kernel(
    const float* __restrict__ x, u16* __restrict__ x_t)
{
  __shared__ u16 sh[64 * 66];
  const int t = threadIdx.x;
  const int p0 = blockIdx.x * 64;
  const int b  = blockIdx.y;
  const int c0 = blockIdx.z * 64;
  const float* xb = x + ((size_t)b * 256 + c0) * NPIX + p0;
  #pragma unroll
  for (int it = 0; it < 16; ++it) {
    int ch = it * 4 + (t >> 6), pix = t & 63;
    sh[pix * 66 + ch] = f2bf(xb[(size_t)ch * NPIX + pix]);
  }
  __syncthreads();
  u16* ob = x_t + ((size_t)b * NPIX + p0) * 256 + c0;
  const unsigned int* sh32 = (const unsigned int*)sh;
  #pragma unroll
  for (int it = 0; it < 8; ++it) {
    int flat = it * 256 + t;
    int pix = flat >> 5, c2 = flat & 31;
    ((unsigned int*)(ob + (size_t)pix * 256))[c2] = sh32[pix * 33 + c2];
  }
}

// ---------------- K1: triple projection via MFMA ----------------
__global__ __launch_bounds__(256) void projmm_kernel(
    const u16* __restrict__ x_t, const u16* __restrict__ Wb,
    u16* __restrict__ Qb, u16* __restrict__ Kb, u16* __restrict__ Vb)
{
  __shared__ u16 Ws[256 * 40];   // [dim][32+pad]
  __shared__ u16 Xs[64 * 40];    // [pix][32+pad]
  const int t = threadIdx.x;
  const int lane = t & 63, wv = t >> 6;
  const int p0 = blockIdx.x * 64;
  const int b  = blockIdx.y;
  const int mat = blockIdx.z;

  const u16* Wm = Wb + (size_t)mat * 65536;
  const u16* Xb = x_t + ((size_t)b * NPIX + p0) * 256;

  f32x4 acc[4][4];
  #pragma unroll
  for (int i = 0; i < 4; ++i)
    #pragma unroll
    for (int j = 0; j < 4; ++j) acc[i][j] = {0.f, 0.f, 0.f, 0.f};

  for (int kk = 0; kk < 8; ++kk) {
    #pragma unroll
    for (int p = 0; p < 4; ++p) {
      int fl = t + 256 * p;
      int d = fl >> 2, c = fl & 3;
      uint4 u = *(const uint4*)(Wm + d * 256 + kk * 32 + c * 8);
      *(uint4*)&Ws[d * 40 + c * 8] = u;
    }
    {
      int pix = t >> 2, c = t & 3;
      uint4 u = *(const uint4*)(Xb + (size_t)pix * 256 + kk * 32 + c * 8);
      *(uint4*)&Xs[pix * 40 + c * 8] = u;
    }
    __syncthreads();
    bf16x8 af[4], bfr[4];
    #pragma unroll
    for (int f = 0; f < 4; ++f)
      af[f] = *(const bf16x8*)&Ws[(wv * 64 + f * 16 + (lane & 15)) * 40 + (lane >> 4) * 8];
    #pragma unroll
    for (int f = 0; f < 4; ++f)
      bfr[f] = *(const bf16x8*)&Xs[(f * 16 + (lane & 15)) * 40 + (lane >> 4) * 8];
    #pragma unroll
    for (int df = 0; df < 4; ++df)
      #pragma unroll
      for (int pf = 0; pf < 4; ++pf)
        acc[df][pf] = __builtin_amdgcn_mfma_f32_16x16x32_bf16(af[df], bfr[pf], acc[df][pf], 0, 0, 0);
    __syncthreads();
  }

  u16* O = (mat == 0) ? Qb : (mat == 1) ? Kb : Vb;
  #pragma unroll
  for (int df = 0; df < 4; ++df) {
    int dim0 = wv * 64 + df * 16 + (lane >> 4) * 4;
    int h = dim0 >> 5, dl0 = dim0 & 31;
    #pragma unroll
    for (int pf = 0; pf < 4; ++pf) {
      int pix = p0 + pf * 16 + (lane & 15);
      f32x4 v = acc[df][pf];
      uint2 u;
      u.x = pk2(v[0], v[1]);
      u.y = pk2(v[2], v[3]);
      *(uint2*)&O[((size_t)(b * 8 + h) * NPIX + pix) * 32 + dl0] = u;
    }
  }
}

// ---------------- K2: fused window attention, 1 wave per (window, head) ----------------
// MFMA QK^T + MFMA PV with bf16 hi/lo error-compensated A (effective f32 A).
__global__ __launch_bounds__(64) void attn_kernel(
    const u16* __restrict__ Qb,   // bf16 [b8h][pix][32]
    const u16* __restrict__ Kb,
    const u16* __restrict__ Vb,
    u16* __restrict__ AO)         // bf16 [b8h][pix][32]
{
  // smem carve (u16 offsets). qs/ks are dead after QK^T; Ahi/Alo alias that region.
  __shared__ __align__(16) u16 smem[10812];   // 21624 B
  u16* qs  = smem;                            // [32][40]
  u16* ks  = smem + 1280;                     // [64][40]
  u16* Ahi = smem;                            // [32][72]  (aliases qs/ks, used post-QK)
  u16* Alo = smem + 2304;                     // [32][72]
  u16* vsT = smem + 4608;                     // [32][72]  V transposed [d][pp]
  float* SA = (float*)(smem + 6912);          // [25][52] f32 S
  float* cb = (float*)(smem + 9512);          // [2][25][13]

  const int lane = threadIdx.x;
  const int bid = blockIdx.x;
  const int h = bid / 2304;
  const int w = bid % 2304;
  const int b = w / 576;
  const int rr = w % 576;
  const int by = rr / 24, bx = rr % 24;
  const int y0 = by * 5, x0 = bx * 5;
  const size_t sbase = (size_t)(b * 8 + h) * XS;
  const u16* Qg = Qb + sbase;
  const u16* Kg = Kb + sbase;
  const u16* Vg = Vb + sbase;

  // --- stage Q (raw bf16, rows 0..24 data, rows 25..31 zero) ---
  #pragma unroll
  for (int it = 0; it < 2; ++it) {
    int idx = lane + 64 * it;           // 0..127
    int pixw = idx >> 2, c = idx & 3;
    uint4 u = make_uint4(0u, 0u, 0u, 0u);
    if (idx < 100) {
      int wy = (pixw * 13) >> 6, wx = pixw - wy * 5;
      u = *(const uint4*)(Qg + ((size_t)((y0 + wy) * IMGW + x0 + wx)) * 32 + c * 8);
    }
    *(uint4*)&qs[pixw * 40 + c * 8] = u;
  }

  // --- stage K halo rows [64][32] (zero-fill pp>=49 and OOB) ---
  #pragma unroll
  for (int it = 0; it < 4; ++it) {
    int f = lane + 64 * it;
    int pp = f >> 2, c = f & 3;
    int hy = (pp * 37) >> 8, hx = pp - hy * 7;
    int gy = y0 - 1 + hy, gx = x0 - 1 + hx;
    uint4 u = make_uint4(0u, 0u, 0u, 0u);
    if (pp < 49 && gy >= 0 && gy < IMGH && gx >= 0 && gx < IMGW)
      u = *(const uint4*)(Kg + (size_t)(gy * IMGW + gx) * 32 + c * 8);
    *(uint4*)&ks[pp * 40 + c * 8] = u;
  }

  // --- stage V transposed: vsT[d][pp], zero-filled pads ---
  #pragma unroll
  for (int it = 0; it < 4; ++it) {
    int f = lane + 64 * it;
    int pp = f >> 2, c = f & 3;
    int hy = (pp * 37) >> 8, hx = pp - hy * 7;
    int gy = y0 - 1 + hy, gx = x0 - 1 + hx;
    uint4 u = make_uint4(0u, 0u, 0u, 0u);
    if (pp < 49 && gy >= 0 && gy < IMGH && gx >= 0 && gx < IMGW)
      u = *(const uint4*)(Vg + (size_t)(gy * IMGW + gx) * 32 + c * 8);
    const int d0 = c * 8;
    vsT[(d0 + 0) * 72 + pp] = (u16)(u.x & 0xffff);
    vsT[(d0 + 1) * 72 + pp] = (u16)(u.x >> 16);
    vsT[(d0 + 2) * 72 + pp] = (u16)(u.y & 0xffff);
    vsT[(d0 + 3) * 72 + pp] = (u16)(u.y >> 16);
    vsT[(d0 + 4) * 72 + pp] = (u16)(u.z & 0xffff);
    vsT[(d0 + 5) * 72 + pp] = (u16)(u.z >> 16);
    vsT[(d0 + 6) * 72 + pp] = (u16)(u.w & 0xffff);
    vsT[(d0 + 7) * 72 + pp] = (u16)(u.w >> 16);
  }
  __syncthreads();

  const int r0 = (lane >> 4) * 4, cc = lane & 15;

  // --- QK^T via MFMA: S[q][pp] ---
  {
    const f32x4 z = {0.f, 0.f, 0.f, 0.f};
    bf16x8 aq0 = *(const bf16x8*)&qs[cc * 40 + (lane >> 4) * 8];
    bf16x8 aq1 = *(const bf16x8*)&qs[(cc + 16) * 40 + (lane >> 4) * 8];
    f32x4 s[2][4];
    #pragma unroll
    for (int nt = 0; nt < 4; ++nt) {
      bf16x8 bk = *(const bf16x8*)&ks[(cc + nt * 16) * 40 + (lane >> 4) * 8];
      s[0][nt] = __builtin_amdgcn_mfma_f32_16x16x32_bf16(aq0, bk, z, 0, 0, 0);
      s[1][nt] = __builtin_amdgcn_mfma_f32_16x16x32_bf16(aq1, bk, z, 0, 0, 0);
    }
    #pragma unroll
    for (int mt = 0; mt < 2; ++mt)
      #pragma unroll
      for (int nt = 0; nt < 4; ++nt)
        #pragma unroll
        for (int i = 0; i < 4; ++i) {
          int q = mt * 16 + r0 + i, pp = nt * 16 + cc;
          if (q < 25 && pp < 49) SA[q * 52 + pp] = s[mt][nt][i];
        }
  }
  __syncthreads();

  // --- zero A rows 25..31 (qs/ks now dead; Ahi/Alo live here) ---
  {
    unsigned int* A32 = (unsigned int*)smem;
    #pragma unroll
    for (int f = lane; f < 252; f += 64) {   // 7 rows * 36 uints
      A32[900 + f]  = 0u;   // Ahi rows 25..31
      A32[2052 + f] = 0u;   // Alo rows 25..31
    }
  }

  // --- expand -> softmax -> fold; fold writes A rows as bf16 hi/lo pair ---
  const float NEG = -0.5f, DPN = 11.f/6.f, NORc = -0.375f;
  for (int t = 0; t < 13; ++t) {
    const int half = lane >> 5, kpl = lane & 31;
    const int q = 2 * t + half;
    const bool act = (kpl < 25) && (q < 25);
    float l[9];
    float m = -1e30f;
    if (act) {
      int ky = kpl / 5, kx = kpl % 5;
      float s9[9];
      #pragma unroll
      for (int dy = 0; dy < 3; ++dy)
        #pragma unroll
        for (int dx = 0; dx < 3; ++dx)
          s9[dy*3+dx] = SA[q * 52 + (ky + dy) * 7 + (kx + dx)];
      float st = ((s9[0]+s9[1]) + (s9[2]+s9[3])) + ((s9[5]+s9[6]) + (s9[7]+s9[8])) + s9[4];
      l[0] = NORc * st + 4.375f * s9[4];
      float base = NEG * st + DPN * s9[4];
      l[1] = base + DPN * (s9[1] + s9[7]);
      l[2] = base + DPN * (s9[3] + s9[5]);
      l[3] = base + DPN * (s9[0] + s9[8]);
      l[4] = base + DPN * (s9[2] + s9[6]);
      l[5] = base + DPN * (s9[1] + s9[3]);
      l[6] = base + DPN * (s9[1] + s9[5]);
      l[7] = base + DPN * (s9[3] + s9[7]);
      l[8] = base + DPN * (s9[5] + s9[7]);
      #pragma unroll
      for (int i = 0; i < 9; ++i) m = fmaxf(m, l[i]);
    }
    #pragma unroll
    for (int o = 16; o >= 1; o >>= 1) m = fmaxf(m, __shfl_xor(m, o));
    float p[9]; float psum = 0.f;
    if (act) {
      #pragma unroll
      for (int i = 0; i < 9; ++i) { p[i] = __expf(l[i] - m); psum += p[i]; }
    }
    float s = act ? psum : 0.f;
    #pragma unroll
    for (int o = 16; o >= 1; o >>= 1) s += __shfl_xor(s, o);
    float rinv = 1.f / s;
    if (act) {
      float psm0  = psum - p[0];
      float basec = NEG * psm0 + NORc * p[0];
      float c[9];
      c[0] = basec + DPN * p[3];
      c[1] = basec + DPN * ((p[1] + p[5]) + p[6]);
      c[2] = basec + DPN * p[4];
      c[3] = basec + DPN * ((p[2] + p[5]) + p[7]);
      c[4] = 4.f * p[0] + (4.f/3.f) * psm0;
      c[5] = basec + DPN * ((p[2] + p[6]) + p[8]);
      c[6] = basec + DPN * p[4];
      c[7] = basec + DPN * ((p[1] + p[7]) + p[8]);
      c[8] = basec + DPN * p[3];
      float* cw = &cb[(half * 25 + kpl) * 13];
      #pragma unroll
      for (int i = 0; i < 9; ++i) cw[i] = c[i] * rinv;
    }
    __syncthreads();
    #pragma unroll
    for (int pass = 0; pass < 2; ++pass) {
      int qg = 2 * t + pass;
      if (qg < 25) {
        float a = 0.f;
        if (lane < 49) {
          int hy = (lane * 37) >> 8, hx = lane - hy * 7;
          #pragma unroll
          for (int dy = 0; dy < 3; ++dy) {
            int ky = hy - dy;
            if ((unsigned)ky < 5u) {
              #pragma unroll
              for (int dx = 0; dx < 3; ++dx) {
                int kx = hx - dx;
                if ((unsigned)kx < 5u)
                  a += cb[(pass * 25 + ky * 5 + kx) * 13 + dy * 3 + dx];
              }
            }
          }
        }
        u16 hi = f2bf(a);
        Ahi[qg * 72 + lane] = hi;
        Alo[qg * 72 + lane] = f2bf(a - bf2f(hi));
      }
    }
    __syncthreads();
  }

  // --- PV via MFMA with hi/lo compensated A: O[q][d] ---
  {
    f32x4 o[2][2];
    #pragma unroll
    for (int i = 0; i < 2; ++i)
      #pragma unroll
      for (int j = 0; j < 2; ++j) o[i][j] = {0.f, 0.f, 0.f, 0.f};
    #pragma unroll
    for (int kx = 0; kx < 2; ++kx) {
      const int ko = kx * 32 + (lane >> 4) * 8;
      bf16x8 ah0 = *(const bf16x8*)&Ahi[cc * 72 + ko];
      bf16x8 ah1 = *(const bf16x8*)&Ahi[(cc + 16) * 72 + ko];
      bf16x8 al0 = *(const bf16x8*)&Alo[cc * 72 + ko];
      bf16x8 al1 = *(const bf16x8*)&Alo[(cc + 16) * 72 + ko];
      bf16x8 b0  = *(const bf16x8*)&vsT[cc * 72 + ko];
      bf16x8 b1  = *(const bf16x8*)&vsT[(cc + 16) * 72 + ko];
      o[0][0] = __builtin_amdgcn_mfma_f32_16x16x32_bf16(ah0, b0, o[0][0], 0, 0, 0);
      o[0][0] = __builtin_amdgcn_mfma_f32_16x16x32_bf16(al0, b0, o[0][0], 0, 0, 0);
      o[0][1] = __builtin_amdgcn_mfma_f32_16x16x32_bf16(ah0, b1, o[0][1], 0, 0, 0);
      o[0][1] = __builtin_amdgcn_mfma_f32_16x16x32_bf16(al0, b1, o[0][1], 0, 0, 0);
      o[1][0] = __builtin_amdgcn_mfma_f32_16x16x32_bf16(ah1, b0, o[1][0], 0, 0, 0);
      o[1][0] = __builtin_amdgcn_mfma_f32_16x16x32_bf16(al1, b0, o[1][0], 0, 0, 0);
      o[1][1] = __builtin_amdgcn_mfma_f32_16x16x32_bf16(ah1, b1, o[1][1], 0, 0, 0);
      o[1][1] = __builtin_amdgcn_mfma_f32_16x16x32_bf16(al1, b1, o[1][1], 0, 0, 0);
    }
    #pragma unroll
    for (int mt = 0; mt < 2; ++mt)
      #pragma unroll
      for (int i = 0; i < 4; ++i) {
        int q = mt * 16 + r0 + i;
        if (q < 25) {
          int qy = (q * 13) >> 6, qx = q - qy * 5;
          u16* dst = AO + sbase + ((size_t)((y0 + qy) * IMGW + x0 + qx)) * 32;
          dst[cc]      = f2bf(o[mt][0][i]);
          dst[cc + 16] = f2bf(o[mt][1][i]);
        }
      }
  }
}

// ---------------- K3: output projection via MFMA ----------------
__global__ __launch_bounds__(256) void outmm_kernel(
    const u16* __restrict__ AOb, const u16* __restrict__ Wb,
    const float* __restrict__ bout, float* __restrict__ O)
{
  __shared__ u16 Ws[256 * 40];
  __shared__ u16 Xs[64 * 40];
  const int t = threadIdx.x;
  const int lane = t & 63, wv = t >> 6;
  const int p0 = blockIdx.x * 64;
  const int b  = blockIdx.y;
  const u16* Wm = Wb + (size_t)3 * 65536;

  f32x4 acc[4][4];
  #pragma unroll
  for (int i = 0; i < 4; ++i)
    #pragma unroll
    for (int j = 0; j < 4; ++j) acc[i][j] = {0.f, 0.f, 0.f, 0.f};

  for (int kk = 0; kk < 8; ++kk) {
    #pragma unroll
    for (int p = 0; p < 4; ++p) {
      int fl = t + 256 * p;
      int d = fl >> 2, c = fl & 3;
      uint4 u = *(const uint4*)(Wm + d * 256 + kk * 32 + c * 8);
      *(uint4*)&Ws[d * 40 + c * 8] = u;
    }
    {
      int pix = t >> 2, c = t & 3;
      uint4 u = *(const uint4*)(AOb + ((size_t)(b * 8 + kk) * NPIX + p0 + pix) * 32 + c * 8);
      *(uint4*)&Xs[pix * 40 + c * 8] = u;
    }
    __syncthreads();
    bf16x8 af[4], bfr[4];
    #pragma unroll
    for (int f = 0; f < 4; ++f)
      af[f] = *(const bf16x8*)&Ws[(wv * 64 + f * 16 + (lane & 15)) * 40 + (lane >> 4) * 8];
    #pragma unroll
    for (int f = 0; f < 4; ++f)
      bfr[f] = *(const bf16x8*)&Xs[(f * 16 + (lane & 15)) * 40 + (lane >> 4) * 8];
    #pragma unroll
    for (int df = 0; df < 4; ++df)
      #pragma unroll
      for (int pf = 0; pf < 4; ++pf)
        acc[df][pf] = __builtin_amdgcn_mfma_f32_16x16x32_bf16(af[df], bfr[pf], acc[df][pf], 0, 0, 0);
    __syncthreads();
  }

  #pragma unroll
  for (int df = 0; df < 4; ++df) {
    int dim0 = wv * 64 + df * 16 + (lane >> 4) * 4;
    float4 bv = *(const float4*)&bout[dim0];
    #pragma unroll
    for (int pf = 0; pf < 4; ++pf) {
      int pix = p0 + pf * 16 + (lane & 15);
      f32x4 v = acc[df][pf];
      float* ob = O + (size_t)b * 256 * NPIX + pix;
      ob[(size_t)(dim0 + 0) * NPIX] = v[0] + bv.x;
      ob[(size_t)(dim0 + 1) * NPIX] = v[1] + bv.y;
      ob[(size_t)(dim0 + 2) * NPIX] = v[2] + bv.z;
      ob[(size_t)(dim0 + 3) * NPIX] = v[3] + bv.w;
    }
  }
}

extern "C" void kernel_launch(void* const* d_in, const int* in_sizes, int n_in,
                              void* d_out, int out_size, void* d_ws, size_t ws_size,
                              hipStream_t stream) {
  const float* x    = (const float*)d_in[0];
  const float* Wk   = (const float*)d_in[2];
  const float* Wv   = (const float*)d_in[3];
  const float* Wq   = (const float*)d_in[4];
  const float* Wout = (const float*)d_in[5];
  const float* bout = (const float*)d_in[6];

  // d_out: x_t bf16 (29,491,200 B) | Qb bf16 (29,491,200 B) — exact fit
  u16* x_t = (u16*)d_out;
  u16* Qb  = x_t + (size_t)4 * NPIX * 256;
  // ws: Kb | Vb | AOb (bf16) | Wb
  u16* Kb  = (u16*)d_ws;
  u16* Vb  = Kb + (size_t)4 * NPIX * 256;
  u16* AOb = Vb + (size_t)4 * NPIX * 256;
  u16* Wb  = AOb + (size_t)4 * NPIX * 256;

  wconv_kernel<<<dim3(64, 4), 256, 0, stream>>>(Wq, Wk, Wv, Wout, Wb);
  xpose_kernel<<<dim3(225, 4, 4), 256, 0, stream>>>(x, x_t);
  projmm_kernel<<<dim3(225, 4, 3), 256, 0, stream>>>(x_t, Wb, Qb, Kb, Vb);
  attn_kernel<<<dim3(18432), 64, 0, stream>>>(Qb, Kb, Vb, AOb);
  outmm_kernel<<<dim3(225, 4), 256, 0, stream>>>(AOb, Wb, bout, (float*)d_out);
}

// Round 7
// 221.533 us; speedup vs baseline: 7.8832x; 1.7236x over previous
//
#include <hip/hip_runtime.h>

#define IMGW 120
#define IMGH 120
#define NPIX 14400      // 120*120
#define XS   460800     // per (b,h) slice stride in elements = 14400*32

typedef unsigned short u16;
typedef short bf16x8 __attribute__((ext_vector_type(8)));
typedef float f32x4 __attribute__((ext_vector_type(4)));

__device__ inline u16 f2bf(float f) {
  unsigned int x = __float_as_uint(f);
  unsigned int r = x + 0x7FFFu + ((x >> 16) & 1u);
  return (u16)(r >> 16);
}
__device__ inline unsigned int pk2(float a, float b) {
  return (unsigned int)f2bf(a) | ((unsigned int)f2bf(b) << 16);
}
__device__ inline float bf2f(u16 h) { return __uint_as_float(((unsigned int)h) << 16); }

// ---------------- P1: weight convert f32 -> bf16 (Wq pre-scaled by 32^-0.5) ----------------
__global__ __launch_bounds__(256) void wconv_kernel(
    const float* __restrict__ Wq, const float* __restrict__ Wk,
    const float* __restrict__ Wv, const float* __restrict__ Wo,
    u16* __restrict__ Wb)
{
  const int t = threadIdx.x, bx = blockIdx.x, mat = blockIdx.y;
  const float* src = mat == 0 ? Wq : mat == 1 ? Wk : mat == 2 ? Wv : Wo;
  const float sc = (mat == 0) ? 0.17677669529663687f : 1.0f;
  const int e0 = (bx * 256 + t) * 4;
  float4 v = *(const float4*)(src + e0);
  uint2 u;
  u.x = pk2(v.x * sc, v.y * sc);
  u.y = pk2(v.z * sc, v.w * sc);
  *(uint2*)(Wb + (size_t)mat * 65536 + e0) = u;
}

// ---------------- P2: transpose-convert x [b][ch][pix] f32 -> x_t [b][pix][256] bf16 ----------------
__global__ __launch_bounds__(256) void xpose_kernel(
    const float* __restrict__ x, u16* __restrict__ x_t)
{
  __shared__ u16 sh[64 * 66];
  const int t = threadIdx.x;
  const int p0 = blockIdx.x * 64;
  const int b  = blockIdx.y;
  const int c0 = blockIdx.z * 64;
  const float* xb = x + ((size_t)b * 256 + c0) * NPIX + p0;
  #pragma unroll
  for (int it = 0; it < 16; ++it) {
    int ch = it * 4 + (t >> 6), pix = t & 63;
    sh[pix * 66 + ch] = f2bf(xb[(size_t)ch * NPIX + pix]);
  }
  __syncthreads();
  u16* ob = x_t + ((size_t)b * NPIX + p0) * 256 + c0;
  const unsigned int* sh32 = (const unsigned int*)sh;
  #pragma unroll
  for (int it = 0; it < 8; ++it) {
    int flat = it * 256 + t;
    int pix = flat >> 5, c2 = flat & 31;
    ((unsigned int*)(ob + (size_t)pix * 256))[c2] = sh32[pix * 33 + c2];
  }
}

// ---------------- K1: triple projection via MFMA ----------------
__global__ __launch_bounds__(256) void projmm_kernel(
    const u16* __restrict__ x_t, const u16* __restrict__ Wb,
    u16* __restrict__ Qb, u16* __restrict__ Kb, u16* __restrict__ Vb)
{
  __shared__ u16 Ws[256 * 40];   // [dim][32+pad]
  __shared__ u16 Xs[64 * 40];    // [pix][32+pad]
  const int t = threadIdx.x;
  const int lane = t & 63, wv = t >> 6;
  const int p0 = blockIdx.x * 64;
  const int b  = blockIdx.y;
  const int mat = blockIdx.z;

  const u16* Wm = Wb + (size_t)mat * 65536;
  const u16* Xb = x_t + ((size_t)b * NPIX + p0) * 256;

  f32x4 acc[4][4];
  #pragma unroll
  for (int i = 0; i < 4; ++i)
    #pragma unroll
    for (int j = 0; j < 4; ++j) acc[i][j] = {0.f, 0.f, 0.f, 0.f};

  for (int kk = 0; kk < 8; ++kk) {
    #pragma unroll
    for (int p = 0; p < 4; ++p) {
      int fl = t + 256 * p;
      int d = fl >> 2, c = fl & 3;
      uint4 u = *(const uint4*)(Wm + d * 256 + kk * 32 + c * 8);
      *(uint4*)&Ws[d * 40 + c * 8] = u;
    }
    {
      int pix = t >> 2, c = t & 3;
      uint4 u = *(const uint4*)(Xb + (size_t)pix * 256 + kk * 32 + c * 8);
      *(uint4*)&Xs[pix * 40 + c * 8] = u;
    }
    __syncthreads();
    bf16x8 af[4], bfr[4];
    #pragma unroll
    for (int f = 0; f < 4; ++f)
      af[f] = *(const bf16x8*)&Ws[(wv * 64 + f * 16 + (lane & 15)) * 40 + (lane >> 4) * 8];
    #pragma unroll
    for (int f = 0; f < 4; ++f)
      bfr[f] = *(const bf16x8*)&Xs[(f * 16 + (lane & 15)) * 40 + (lane >> 4) * 8];
    #pragma unroll
    for (int df = 0; df < 4; ++df)
      #pragma unroll
      for (int pf = 0; pf < 4; ++pf)
        acc[df][pf] = __builtin_amdgcn_mfma_f32_16x16x32_bf16(af[df], bfr[pf], acc[df][pf], 0, 0, 0);
    __syncthreads();
  }

  u16* O = (mat == 0) ? Qb : (mat == 1) ? Kb : Vb;
  #pragma unroll
  for (int df = 0; df < 4; ++df) {
    int dim0 = wv * 64 + df * 16 + (lane >> 4) * 4;
    int h = dim0 >> 5, dl0 = dim0 & 31;
    #pragma unroll
    for (int pf = 0; pf < 4; ++pf) {
      int pix = p0 + pf * 16 + (lane & 15);
      f32x4 v = acc[df][pf];
      uint2 u;
      u.x = pk2(v[0], v[1]);
      u.y = pk2(v[2], v[3]);
      *(uint2*)&O[((size_t)(b * 8 + h) * NPIX + pix) * 32 + dl0] = u;
    }
  }
}

// ---------------- K2: fused window attention, 1 wave per (window, head) ----------------
// Barrier-free single-wave design: MFMA QK^T (frags direct from global), bpermute fold,
// exp2-shifted softmax with deferred denominator, MFMA PV with hi/lo A, rinv epilogue.
__global__ __launch_bounds__(64, 3) void attn_kernel(
    const u16* __restrict__ Qb,   // bf16 [b8h][pix][32]
    const u16* __restrict__ Kb,
    const u16* __restrict__ Vb,
    u16* __restrict__ AO)         // bf16 [b8h][pix][32]
{
  // 13440 B LDS -> 12 blocks/CU.
  // SA region: 32 rows x 272 B. Early: S[q][pp] f32 (stride 68 f32, cols 0..48).
  //   Row q is consumed by iteration q only, then overlaid by A row q:
  //   hi bf16 at bytes 0..127 (k=0..63), lo bf16 at bytes 128..255.
  __shared__ __align__(16) unsigned char smem[13440];
  float* SA   = (float*)smem;               // stride 68 f32 per row
  u16*   vsT  = (u16*)(smem + 8704);        // [32][72] V transposed [d][pp]
  float* drow = (float*)(smem + 13312);     // [32] rinv per q

  const int lane = threadIdx.x;
  const int bid = blockIdx.x;
  const int h = bid / 2304;
  const int w = bid % 2304;
  const int b = w / 576;
  const int rr = w % 576;
  const int by = rr / 24, bx = rr % 24;
  const int y0 = by * 5, x0 = bx * 5;
  const size_t gbase = (size_t)(b * 8 + h) * XS;
  const u16* Qg = Qb + gbase;
  const u16* Kg = Kb + gbase;
  const u16* Vg = Vb + gbase;

  const int cc = lane & 15, kgrp = lane >> 4;
  const int ks8 = kgrp * 8;
  const int r0 = kgrp * 4;
  const int kpl = lane & 31;

  // --- Q A-frags direct from global (rows q>=25 garbage-inert) ---
  bf16x8 aq0, aq1;
  {
    int rA = cc;                 // < 25 always
    int wyA = (rA * 13) >> 6, wxA = rA - wyA * 5;
    uint4 uA = *(const uint4*)(Qg + (size_t)((y0 + wyA) * IMGW + x0 + wxA) * 32 + ks8);
    aq0 = *(bf16x8*)&uA;
    int rB = cc + 16; int rBc = rB < 25 ? rB : 0;
    int wyB = (rBc * 13) >> 6, wxB = rBc - wyB * 5;
    uint4 uB = *(const uint4*)(Qg + (size_t)((y0 + wyB) * IMGW + x0 + wxB) * 32 + ks8);
    aq1 = *(bf16x8*)&uB;
  }

  // --- K B-frags direct from global (pp<49 OOB -> exact zero; pp>=49 inert) ---
  bf16x8 bk[4];
  #pragma unroll
  for (int nt = 0; nt < 4; ++nt) {
    int pp = cc + nt * 16;
    int hy = (pp * 37) >> 8, hx = pp - hy * 7;
    int gy = y0 - 1 + hy, gx = x0 - 1 + hx;
    bool inb = (gy >= 0) && (gy < IMGH) && (gx >= 0) && (gx < IMGW);
    int gyc = min(max(gy, 0), IMGH - 1), gxc = min(max(gx, 0), IMGW - 1);
    uint4 u = *(const uint4*)(Kg + (size_t)(gyc * IMGW + gxc) * 32 + ks8);
    if (pp < 49 && !inb) u = make_uint4(0u, 0u, 0u, 0u);
    bk[nt] = *(bf16x8*)&u;
  }

  // --- V halo -> vsT[d][pp] (zero-filled) ---
  #pragma unroll
  for (int it = 0; it < 4; ++it) {
    int f = lane + 64 * it;
    int pp = f >> 2, c = f & 3;
    int hy = (pp * 37) >> 8, hx = pp - hy * 7;
    int gy = y0 - 1 + hy, gx = x0 - 1 + hx;
    uint4 u = make_uint4(0u, 0u, 0u, 0u);
    if (pp < 49 && gy >= 0 && gy < IMGH && gx >= 0 && gx < IMGW)
      u = *(const uint4*)(Vg + (size_t)(gy * IMGW + gx) * 32 + c * 8);
    const int d0 = c * 8;
    vsT[(d0 + 0) * 72 + pp] = (u16)(u.x & 0xffff);
    vsT[(d0 + 1) * 72 + pp] = (u16)(u.x >> 16);
    vsT[(d0 + 2) * 72 + pp] = (u16)(u.y & 0xffff);
    vsT[(d0 + 3) * 72 + pp] = (u16)(u.y >> 16);
    vsT[(d0 + 4) * 72 + pp] = (u16)(u.z & 0xffff);
    vsT[(d0 + 5) * 72 + pp] = (u16)(u.z >> 16);
    vsT[(d0 + 6) * 72 + pp] = (u16)(u.w & 0xffff);
    vsT[(d0 + 7) * 72 + pp] = (u16)(u.w >> 16);
  }

  // --- QK^T via MFMA, scatter to SA (same-wave DS ordering, no barrier) ---
  {
    const f32x4 z = {0.f, 0.f, 0.f, 0.f};
    f32x4 s[2][4];
    #pragma unroll
    for (int nt = 0; nt < 4; ++nt) {
      s[0][nt] = __builtin_amdgcn_mfma_f32_16x16x32_bf16(aq0, bk[nt], z, 0, 0, 0);
      s[1][nt] = __builtin_amdgcn_mfma_f32_16x16x32_bf16(aq1, bk[nt], z, 0, 0, 0);
    }
    #pragma unroll
    for (int mt = 0; mt < 2; ++mt)
      #pragma unroll
      for (int nt = 0; nt < 4; ++nt)
        #pragma unroll
        for (int i = 0; i < 4; ++i) {
          int q = mt * 16 + r0 + i, pp = nt * 16 + cc;
          if (q < 25 && pp < 49) SA[q * 68 + pp] = s[mt][nt][i];
        }
  }

  // --- fold constants (loop-invariant): src lanes + validity for both passes ---
  int idxA[9], idxB[9];
  float selA[9], selB[9];
  {
    const int hb = lane & 32;
    const int ppA = kpl, ppB = 32 + kpl;
    const int hyA = (ppA * 37) >> 8, hxA = ppA - hyA * 7;
    const int hyB = (ppB * 37) >> 8, hxB = ppB - hyB * 7;
    #pragma unroll
    for (int dy = 0; dy < 3; ++dy)
      #pragma unroll
      for (int dx = 0; dx < 3; ++dx) {
        int j = dy * 3 + dx;
        int kyA = hyA - dy, kxA = hxA - dx;
        bool vA = ((unsigned)kyA < 5u) && ((unsigned)kxA < 5u);
        idxA[j] = (hb + (vA ? kyA * 5 + kxA : 0)) << 2;
        selA[j] = vA ? 1.f : 0.f;
        int kyB = hyB - dy, kxB = hxB - dx;
        bool vB = ((unsigned)kyB < 5u) && ((unsigned)kxB < 5u);
        idxB[j] = (hb + (vB ? kyB * 5 + kxB : 0)) << 2;
        selB[j] = vB ? 1.f : 0.f;
      }
  }

  // --- expand -> exp2-shifted softmax -> bpermute fold (barrier-free) ---
  const float DPN = 11.f / 6.f;
  const float LOG2E = 1.44269504f;
  const int kyq = (kpl * 13) >> 6, kxq = kpl - kyq * 5;
  const int sboff = kyq * 7 + kxq;

  for (int t = 0; t < 13; ++t) {
    const int q = 2 * t + (lane >> 5);
    const bool act = (kpl < 25) && (q < 25);
    const float* sp = SA + q * 68 + sboff;
    float s0 = sp[0], s1 = sp[1], s2 = sp[2];
    float s3 = sp[7], s4 = sp[8], s5 = sp[9];
    float s6 = sp[14], s7 = sp[15], s8 = sp[16];

    float st = ((s0 + s1) + (s2 + s3)) + ((s5 + s6) + (s7 + s8)) + s4;
    float l0 = -0.375f * st + 4.375f * s4;
    float base = -0.5f * st + DPN * s4;
    float l1 = base + DPN * (s1 + s7);
    float l2 = base + DPN * (s3 + s5);
    float l3 = base + DPN * (s0 + s8);
    float l4 = base + DPN * (s2 + s6);
    float l5 = base + DPN * (s1 + s3);
    float l6 = base + DPN * (s1 + s5);
    float l7 = base + DPN * (s3 + s7);
    float l8 = base + DPN * (s5 + s7);

    float p0 = exp2f(fmaf(l0, LOG2E, -32.f));
    float p1 = exp2f(fmaf(l1, LOG2E, -32.f));
    float p2 = exp2f(fmaf(l2, LOG2E, -32.f));
    float p3 = exp2f(fmaf(l3, LOG2E, -32.f));
    float p4 = exp2f(fmaf(l4, LOG2E, -32.f));
    float p5 = exp2f(fmaf(l5, LOG2E, -32.f));
    float p6 = exp2f(fmaf(l6, LOG2E, -32.f));
    float p7 = exp2f(fmaf(l7, LOG2E, -32.f));
    float p8 = exp2f(fmaf(l8, LOG2E, -32.f));
    float ps = ((p0 + p1) + (p2 + p3)) + ((p4 + p5) + (p6 + p7)) + p8;

    // denominator reduce over 32-lane half: 2 DPP quad-perm adds + 3 shfl_xor
    float sv = act ? ps : 0.f;
    sv += __int_as_float(__builtin_amdgcn_update_dpp(0, __float_as_int(sv), 0xB1, 0xF, 0xF, true));
    sv += __int_as_float(__builtin_amdgcn_update_dpp(0, __float_as_int(sv), 0x4E, 0xF, 0xF, true));
    sv += __shfl_xor(sv, 4);
    sv += __shfl_xor(sv, 8);
    sv += __shfl_xor(sv, 16);
    if (kpl == 0 && q < 25) drow[q] = __builtin_amdgcn_rcpf(sv + 1e-35f);

    // per-offset fold coefficients (unscaled; rinv deferred to PV epilogue)
    float psm0 = ps - p0;
    float basec = -0.5f * psm0 - 0.375f * p0;
    float cv[9];
    cv[0] = basec + DPN * p3;
    cv[1] = basec + DPN * ((p1 + p5) + p6);
    cv[2] = basec + DPN * p4;
    cv[3] = basec + DPN * ((p2 + p5) + p7);
    cv[4] = 4.f * p0 + (4.f / 3.f) * psm0;
    cv[5] = basec + DPN * ((p2 + p6) + p8);
    cv[6] = basec + DPN * p4;
    cv[7] = basec + DPN * ((p1 + p7) + p8);
    cv[8] = basec + DPN * p3;

    // fold via bpermute: pass A -> pp = kpl, pass B -> pp = 32+kpl
    float a = 0.f, a2 = 0.f;
    #pragma unroll
    for (int j = 0; j < 9; ++j) {
      int cj = __float_as_int(cv[j]);
      a  = fmaf(selA[j], __int_as_float(__builtin_amdgcn_ds_bpermute(idxA[j], cj)), a);
      a2 = fmaf(selB[j], __int_as_float(__builtin_amdgcn_ds_bpermute(idxB[j], cj)), a2);
    }

    if (q < 25) {
      u16* arow = (u16*)((char*)SA + q * 272);
      u16 h1 = f2bf(a);
      arow[kpl]      = h1;
      arow[64 + kpl] = f2bf(a - bf2f(h1));
      u16 h2 = f2bf(a2);
      arow[32 + kpl] = h2;
      arow[96 + kpl] = f2bf(a2 - bf2f(h2));
    }
  }

  __syncthreads();   // single barrier: A/drow/vsT -> PV frag reads (alias-cast safety)

  // --- PV via MFMA (hi/lo compensated A), rinv epilogue ---
  {
    f32x4 o[2][2];
    #pragma unroll
    for (int i = 0; i < 2; ++i)
      #pragma unroll
      for (int j = 0; j < 2; ++j) o[i][j] = {0.f, 0.f, 0.f, 0.f};
    #pragma unroll
    for (int kx = 0; kx < 2; ++kx) {
      const int koff = kx * 64 + kgrp * 16;         // byte offset within hi block
      const char* sa = (const char*)SA;
      bf16x8 ah0 = *(const bf16x8*)(sa + cc * 272 + koff);
      bf16x8 ah1 = *(const bf16x8*)(sa + (cc + 16) * 272 + koff);
      bf16x8 al0 = *(const bf16x8*)(sa + cc * 272 + 128 + koff);
      bf16x8 al1 = *(const bf16x8*)(sa + (cc + 16) * 272 + 128 + koff);
      bf16x8 b0  = *(const bf16x8*)&vsT[cc * 72 + kx * 32 + ks8];
      bf16x8 b1  = *(const bf16x8*)&vsT[(cc + 16) * 72 + kx * 32 + ks8];
      o[0][0] = __builtin_amdgcn_mfma_f32_16x16x32_bf16(ah0, b0, o[0][0], 0, 0, 0);
      o[0][0] = __builtin_amdgcn_mfma_f32_16x16x32_bf16(al0, b0, o[0][0], 0, 0, 0);
      o[0][1] = __builtin_amdgcn_mfma_f32_16x16x32_bf16(ah0, b1, o[0][1], 0, 0, 0);
      o[0][1] = __builtin_amdgcn_mfma_f32_16x16x32_bf16(al0, b1, o[0][1], 0, 0, 0);
      o[1][0] = __builtin_amdgcn_mfma_f32_16x16x32_bf16(ah1, b0, o[1][0], 0, 0, 0);
      o[1][0] = __builtin_amdgcn_mfma_f32_16x16x32_bf16(al1, b0, o[1][0], 0, 0, 0);
      o[1][1] = __builtin_amdgcn_mfma_f32_16x16x32_bf16(ah1, b1, o[1][1], 0, 0, 0);
      o[1][1] = __builtin_amdgcn_mfma_f32_16x16x32_bf16(al1, b1, o[1][1], 0, 0, 0);
    }
    #pragma unroll
    for (int mt = 0; mt < 2; ++mt) {
      float4 rv = *(const float4*)&drow[mt * 16 + r0];
      #pragma unroll
      for (int i = 0; i < 4; ++i) {
        int q = mt * 16 + r0 + i;
        if (q < 25) {
          int qy = (q * 13) >> 6, qx = q - qy * 5;
          u16* dst = AO + gbase + ((size_t)((y0 + qy) * IMGW + x0 + qx)) * 32;
          float r = (&rv.x)[i];
          dst[cc]      = f2bf(o[mt][0][i] * r);
          dst[cc + 16] = f2bf(o[mt][1][i] * r);
        }
      }
    }
  }
}

// ---------------- K3: output projection via MFMA ----------------
__global__ __launch_bounds__(256) void outmm_kernel(
    const u16* __restrict__ AOb, const u16* __restrict__ Wb,
    const float* __restrict__ bout, float* __restrict__ O)
{
  __shared__ u16 Ws[256 * 40];
  __shared__ u16 Xs[64 * 40];
  const int t = threadIdx.x;
  const int lane = t & 63, wv = t >> 6;
  const int p0 = blockIdx.x * 64;
  const int b  = blockIdx.y;
  const u16* Wm = Wb + (size_t)3 * 65536;

  f32x4 acc[4][4];
  #pragma unroll
  for (int i = 0; i < 4; ++i)
    #pragma unroll
    for (int j = 0; j < 4; ++j) acc[i][j] = {0.f, 0.f, 0.f, 0.f};

  for (int kk = 0; kk < 8; ++kk) {
    #pragma unroll
    for (int p = 0; p < 4; ++p) {
      int fl = t + 256 * p;
      int d = fl >> 2, c = fl & 3;
      uint4 u = *(const uint4*)(Wm + d * 256 + kk * 32 + c * 8);
      *(uint4*)&Ws[d * 40 + c * 8] = u;
    }
    {
      int pix = t >> 2, c = t & 3;
      uint4 u = *(const uint4*)(AOb + ((size_t)(b * 8 + kk) * NPIX + p0 + pix) * 32 + c * 8);
      *(uint4*)&Xs[pix * 40 + c * 8] = u;
    }
    __syncthreads();
    bf16x8 af[4], bfr[4];
    #pragma unroll
    for (int f = 0; f < 4; ++f)
      af[f] = *(const bf16x8*)&Ws[(wv * 64 + f * 16 + (lane & 15)) * 40 + (lane >> 4) * 8];
    #pragma unroll
    for (int f = 0; f < 4; ++f)
      bfr[f] = *(const bf16x8*)&Xs[(f * 16 + (lane & 15)) * 40 + (lane >> 4) * 8];
    #pragma unroll
    for (int df = 0; df < 4; ++df)
      #pragma unroll
      for (int pf = 0; pf < 4; ++pf)
        acc[df][pf] = __builtin_amdgcn_mfma_f32_16x16x32_bf16(af[df], bfr[pf], acc[df][pf], 0, 0, 0);
    __syncthreads();
  }

  #pragma unroll
  for (int df = 0; df < 4; ++df) {
    int dim0 = wv * 64 + df * 16 + (lane >> 4) * 4;
    float4 bv = *(const float4*)&bout[dim0];
    #pragma unroll
    for (int pf = 0; pf < 4; ++pf) {
      int pix = p0 + pf * 16 + (lane & 15);
      f32x4 v = acc[df][pf];
      float* ob = O + (size_t)b * 256 * NPIX + pix;
      ob[(size_t)(dim0 + 0) * NPIX] = v[0] + bv.x;
      ob[(size_t)(dim0 + 1) * NPIX] = v[1] + bv.y;
      ob[(size_t)(dim0 + 2) * NPIX] = v[2] + bv.z;
      ob[(size_t)(dim0 + 3) * NPIX] = v[3] + bv.w;
    }
  }
}

extern "C" void kernel_launch(void* const* d_in, const int* in_sizes, int n_in,
                              void* d_out, int out_size, void* d_ws, size_t ws_size,
                              hipStream_t stream) {
  const float* x    = (const float*)d_in[0];
  const float* Wk   = (const float*)d_in[2];
  const float* Wv   = (const float*)d_in[3];
  const float* Wq   = (const float*)d_in[4];
  const float* Wout = (const float*)d_in[5];
  const float* bout = (const float*)d_in[6];

  // d_out: x_t bf16 (29,491,200 B) | Qb bf16 (29,491,200 B) — exact fit
  u16* x_t = (u16*)d_out;
  u16* Qb  = x_t + (size_t)4 * NPIX * 256;
  // ws: Kb | Vb | AOb (bf16) | Wb
  u16* Kb  = (u16*)d_ws;
  u16* Vb  = Kb + (size_t)4 * NPIX * 256;
  u16* AOb = Vb + (size_t)4 * NPIX * 256;
  u16* Wb  = AOb + (size_t)4 * NPIX * 256;

  wconv_kernel<<<dim3(64, 4), 256, 0, stream>>>(Wq, Wk, Wv, Wout, Wb);
  xpose_kernel<<<dim3(225, 4, 4), 256, 0, stream>>>(x, x_t);
  projmm_kernel<<<dim3(225, 4, 3), 256, 0, stream>>>(x_t, Wb, Qb, Kb, Vb);
  attn_kernel<<<dim3(18432), 64, 0, stream>>>(Qb, Kb, Vb, AOb);
  outmm_kernel<<<dim3(225, 4), 256, 0, stream>>>(AOb, Wb, bout, (float*)d_out);
}

// Round 8
// 219.722 us; speedup vs baseline: 7.9482x; 1.0082x over previous
//
#include <hip/hip_runtime.h>

#define IMGW 120
#define IMGH 120
#define NPIX 14400      // 120*120
#define XS   460800     // per (b,h) slice stride in elements = 14400*32

typedef unsigned short u16;
typedef short bf16x8 __attribute__((ext_vector_type(8)));
typedef float f32x4 __attribute__((ext_vector_type(4)));

__device__ inline u16 f2bf(float f) {
  unsigned int x = __float_as_uint(f);
  unsigned int r = x + 0x7FFFu + ((x >> 16) & 1u);
  return (u16)(r >> 16);
}
__device__ inline unsigned int pk2(float a, float b) {
  return (unsigned int)f2bf(a) | ((unsigned int)f2bf(b) << 16);
}
__device__ inline float bf2f(u16 h) { return __uint_as_float(((unsigned int)h) << 16); }

// ---------------- P1: weight convert f32 -> bf16 (Wq pre-scaled by 32^-0.5) ----------------
__global__ __launch_bounds__(256) void wconv_kernel(
    const float* __restrict__ Wq, const float* __restrict__ Wk,
    const float* __restrict__ Wv, const float* __restrict__ Wo,
    u16* __restrict__ Wb)
{
  const int t = threadIdx.x, bx = blockIdx.x, mat = blockIdx.y;
  const float* src = mat == 0 ? Wq : mat == 1 ? Wk : mat == 2 ? Wv : Wo;
  const float sc = (mat == 0) ? 0.17677669529663687f : 1.0f;
  const int e0 = (bx * 256 + t) * 4;
  float4 v = *(const float4*)(src + e0);
  uint2 u;
  u.x = pk2(v.x * sc, v.y * sc);
  u.y = pk2(v.z * sc, v.w * sc);
  *(uint2*)(Wb + (size_t)mat * 65536 + e0) = u;
}

// ---------------- P2: transpose-convert x [b][ch][pix] f32 -> x_t [b][pix][256] bf16 ----------------
__global__ __launch_bounds__(256) void xpose_kernel(
    const float* __restrict__ x, u16* __restrict__ x_t)
{
  __shared__ u16 sh[64 * 66];
  const int t = threadIdx.x;
  const int p0 = blockIdx.x * 64;
  const int b  = blockIdx.y;
  const int c0 = blockIdx.z * 64;
  const float* xb = x + ((size_t)b * 256 + c0) * NPIX + p0;
  #pragma unroll
  for (int it = 0; it < 16; ++it) {
    int ch = it * 4 + (t >> 6), pix = t & 63;
    sh[pix * 66 + ch] = f2bf(xb[(size_t)ch * NPIX + pix]);
  }
  __syncthreads();
  u16* ob = x_t + ((size_t)b * NPIX + p0) * 256 + c0;
  const unsigned int* sh32 = (const unsigned int*)sh;
  #pragma unroll
  for (int it = 0; it < 8; ++it) {
    int flat = it * 256 + t;
    int pix = flat >> 5, c2 = flat & 31;
    ((unsigned int*)(ob + (size_t)pix * 256))[c2] = sh32[pix * 33 + c2];
  }
}

// ---------------- K1: triple projection via MFMA ----------------
__global__ __launch_bounds__(256) void projmm_kernel(
    const u16* __restrict__ x_t, const u16* __restrict__ Wb,
    u16* __restrict__ Qb, u16* __restrict__ Kb, u16* __restrict__ Vb)
{
  __shared__ u16 Ws[256 * 40];   // [dim][32+pad]
  __shared__ u16 Xs[64 * 40];    // [pix][32+pad]
  const int t = threadIdx.x;
  const int lane = t & 63, wv = t >> 6;
  const int p0 = blockIdx.x * 64;
  const int b  = blockIdx.y;
  const int mat = blockIdx.z;

  const u16* Wm = Wb + (size_t)mat * 65536;
  const u16* Xb = x_t + ((size_t)b * NPIX + p0) * 256;

  f32x4 acc[4][4];
  #pragma unroll
  for (int i = 0; i < 4; ++i)
    #pragma unroll
    for (int j = 0; j < 4; ++j) acc[i][j] = {0.f, 0.f, 0.f, 0.f};

  for (int kk = 0; kk < 8; ++kk) {
    #pragma unroll
    for (int p = 0; p < 4; ++p) {
      int fl = t + 256 * p;
      int d = fl >> 2, c = fl & 3;
      uint4 u = *(const uint4*)(Wm + d * 256 + kk * 32 + c * 8);
      *(uint4*)&Ws[d * 40 + c * 8] = u;
    }
    {
      int pix = t >> 2, c = t & 3;
      uint4 u = *(const uint4*)(Xb + (size_t)pix * 256 + kk * 32 + c * 8);
      *(uint4*)&Xs[pix * 40 + c * 8] = u;
    }
    __syncthreads();
    bf16x8 af[4], bfr[4];
    #pragma unroll
    for (int f = 0; f < 4; ++f)
      af[f] = *(const bf16x8*)&Ws[(wv * 64 + f * 16 + (lane & 15)) * 40 + (lane >> 4) * 8];
    #pragma unroll
    for (int f = 0; f < 4; ++f)
      bfr[f] = *(const bf16x8*)&Xs[(f * 16 + (lane & 15)) * 40 + (lane >> 4) * 8];
    #pragma unroll
    for (int df = 0; df < 4; ++df)
      #pragma unroll
      for (int pf = 0; pf < 4; ++pf)
        acc[df][pf] = __builtin_amdgcn_mfma_f32_16x16x32_bf16(af[df], bfr[pf], acc[df][pf], 0, 0, 0);
    __syncthreads();
  }

  u16* O = (mat == 0) ? Qb : (mat == 1) ? Kb : Vb;
  #pragma unroll
  for (int df = 0; df < 4; ++df) {
    int dim0 = wv * 64 + df * 16 + (lane >> 4) * 4;
    int h = dim0 >> 5, dl0 = dim0 & 31;
    #pragma unroll
    for (int pf = 0; pf < 4; ++pf) {
      int pix = p0 + pf * 16 + (lane & 15);
      f32x4 v = acc[df][pf];
      uint2 u;
      u.x = pk2(v[0], v[1]);
      u.y = pk2(v[2], v[3]);
      *(uint2*)&O[((size_t)(b * 8 + h) * NPIX + pix) * 32 + dl0] = u;
    }
  }
}

// ---------------- K2: fused window attention, 1 wave per (window, head) ----------------
// Barrier-free single-wave design: MFMA QK^T (frags direct from global), bpermute fold,
// exp2-shifted softmax with deferred denominator, MFMA PV with hi/lo A, rinv epilogue.
// LDS = 11536 B -> 13 blocks/CU. SA holds 25 real rows; MFMA A-frag reads of
// "rows 25..31" land inside vsT (valid bf16 data, rows inert since D rows >=25 discarded).
__global__ __launch_bounds__(64, 3) void attn_kernel(
    const u16* __restrict__ Qb,   // bf16 [b8h][pix][32]
    const u16* __restrict__ Kb,
    const u16* __restrict__ Vb,
    u16* __restrict__ AO)         // bf16 [b8h][pix][32]
{
  __shared__ __align__(16) unsigned char smem[11536];
  float* SA   = (float*)smem;               // 25 rows x 272 B (stride 68 f32)
  u16*   vsT  = (u16*)(smem + 6800);        // [32][72] V transposed [d][pp]
  float* drow = (float*)(smem + 11408);     // [32] rinv per q

  const int lane = threadIdx.x;
  const int bid = blockIdx.x;
  const int h = bid / 2304;
  const int w = bid % 2304;
  const int b = w / 576;
  const int rr = w % 576;
  const int by = rr / 24, bx = rr % 24;
  const int y0 = by * 5, x0 = bx * 5;
  const size_t gbase = (size_t)(b * 8 + h) * XS;
  const u16* Qg = Qb + gbase;
  const u16* Kg = Kb + gbase;
  const u16* Vg = Vb + gbase;

  const int cc = lane & 15, kgrp = lane >> 4;
  const int ks8 = kgrp * 8;
  const int r0 = kgrp * 4;
  const int kpl = lane & 31;

  // determinism hygiene: drow tail (read as float4, results discarded) gets zeros
  if (lane >= 25 && lane < 32) drow[lane] = 0.f;

  // --- Q A-frags direct from global (rows q>=25 garbage-inert) ---
  bf16x8 aq0, aq1;
  {
    int rA = cc;                 // < 25 always
    int wyA = (rA * 13) >> 6, wxA = rA - wyA * 5;
    uint4 uA = *(const uint4*)(Qg + (size_t)((y0 + wyA) * IMGW + x0 + wxA) * 32 + ks8);
    aq0 = *(bf16x8*)&uA;
    int rB = cc + 16; int rBc = rB < 25 ? rB : 0;
    int wyB = (rBc * 13) >> 6, wxB = rBc - wyB * 5;
    uint4 uB = *(const uint4*)(Qg + (size_t)((y0 + wyB) * IMGW + x0 + wxB) * 32 + ks8);
    aq1 = *(bf16x8*)&uB;
  }

  // --- K B-frags direct from global (pp<49 OOB -> exact zero; pp>=49 inert) ---
  bf16x8 bk[4];
  #pragma unroll
  for (int nt = 0; nt < 4; ++nt) {
    int pp = cc + nt * 16;
    int hy = (pp * 37) >> 8, hx = pp - hy * 7;
    int gy = y0 - 1 + hy, gx = x0 - 1 + hx;
    bool inb = (gy >= 0) && (gy < IMGH) && (gx >= 0) && (gx < IMGW);
    int gyc = min(max(gy, 0), IMGH - 1), gxc = min(max(gx, 0), IMGW - 1);
    uint4 u = *(const uint4*)(Kg + (size_t)(gyc * IMGW + gxc) * 32 + ks8);
    if (pp < 49 && !inb) u = make_uint4(0u, 0u, 0u, 0u);
    bk[nt] = *(bf16x8*)&u;
  }

  // --- V halo -> vsT[d][pp] (zero-filled) ---
  #pragma unroll
  for (int it = 0; it < 4; ++it) {
    int f = lane + 64 * it;
    int pp = f >> 2, c = f & 3;
    int hy = (pp * 37) >> 8, hx = pp - hy * 7;
    int gy = y0 - 1 + hy, gx = x0 - 1 + hx;
    uint4 u = make_uint4(0u, 0u, 0u, 0u);
    if (pp < 49 && gy >= 0 && gy < IMGH && gx >= 0 && gx < IMGW)
      u = *(const uint4*)(Vg + (size_t)(gy * IMGW + gx) * 32 + c * 8);
    const int d0 = c * 8;
    vsT[(d0 + 0) * 72 + pp] = (u16)(u.x & 0xffff);
    vsT[(d0 + 1) * 72 + pp] = (u16)(u.x >> 16);
    vsT[(d0 + 2) * 72 + pp] = (u16)(u.y & 0xffff);
    vsT[(d0 + 3) * 72 + pp] = (u16)(u.y >> 16);
    vsT[(d0 + 4) * 72 + pp] = (u16)(u.z & 0xffff);
    vsT[(d0 + 5) * 72 + pp] = (u16)(u.z >> 16);
    vsT[(d0 + 6) * 72 + pp] = (u16)(u.w & 0xffff);
    vsT[(d0 + 7) * 72 + pp] = (u16)(u.w >> 16);
  }

  // --- QK^T via MFMA, scatter to SA (same-wave DS ordering, no barrier) ---
  {
    const f32x4 z = {0.f, 0.f, 0.f, 0.f};
    f32x4 s[2][4];
    #pragma unroll
    for (int nt = 0; nt < 4; ++nt) {
      s[0][nt] = __builtin_amdgcn_mfma_f32_16x16x32_bf16(aq0, bk[nt], z, 0, 0, 0);
      s[1][nt] = __builtin_amdgcn_mfma_f32_16x16x32_bf16(aq1, bk[nt], z, 0, 0, 0);
    }
    #pragma unroll
    for (int mt = 0; mt < 2; ++mt)
      #pragma unroll
      for (int nt = 0; nt < 4; ++nt)
        #pragma unroll
        for (int i = 0; i < 4; ++i) {
          int q = mt * 16 + r0 + i, pp = nt * 16 + cc;
          if (q < 25 && pp < 49) SA[q * 68 + pp] = s[mt][nt][i];
        }
  }

  // --- fold constants (loop-invariant): src lanes + validity for both passes ---
  int idxA[9], idxB[9];
  float selA[9], selB[9];
  {
    const int hb = lane & 32;
    const int ppA = kpl, ppB = 32 + kpl;
    const int hyA = (ppA * 37) >> 8, hxA = ppA - hyA * 7;
    const int hyB = (ppB * 37) >> 8, hxB = ppB - hyB * 7;
    #pragma unroll
    for (int dy = 0; dy < 3; ++dy)
      #pragma unroll
      for (int dx = 0; dx < 3; ++dx) {
        int j = dy * 3 + dx;
        int kyA = hyA - dy, kxA = hxA - dx;
        bool vA = ((unsigned)kyA < 5u) && ((unsigned)kxA < 5u);
        idxA[j] = (hb + (vA ? kyA * 5 + kxA : 0)) << 2;
        selA[j] = vA ? 1.f : 0.f;
        int kyB = hyB - dy, kxB = hxB - dx;
        bool vB = ((unsigned)kyB < 5u) && ((unsigned)kxB < 5u);
        idxB[j] = (hb + (vB ? kyB * 5 + kxB : 0)) << 2;
        selB[j] = vB ? 1.f : 0.f;
      }
  }

  // --- expand -> exp2-shifted softmax -> bpermute fold (barrier-free) ---
  const float DPN = 11.f / 6.f;
  const float LOG2E = 1.44269504f;
  const int kyq = (kpl * 13) >> 6, kxq = kpl - kyq * 5;
  const int sboff = kyq * 7 + kxq;

  for (int t = 0; t < 13; ++t) {
    const int q = 2 * t + (lane >> 5);
    const bool act = (kpl < 25) && (q < 25);
    const float* sp = SA + q * 68 + sboff;
    float s0 = sp[0], s1 = sp[1], s2 = sp[2];
    float s3 = sp[7], s4 = sp[8], s5 = sp[9];
    float s6 = sp[14], s7 = sp[15], s8 = sp[16];

    float st = ((s0 + s1) + (s2 + s3)) + ((s5 + s6) + (s7 + s8)) + s4;
    float l0 = -0.375f * st + 4.375f * s4;
    float base = -0.5f * st + DPN * s4;
    float l1 = base + DPN * (s1 + s7);
    float l2 = base + DPN * (s3 + s5);
    float l3 = base + DPN * (s0 + s8);
    float l4 = base + DPN * (s2 + s6);
    float l5 = base + DPN * (s1 + s3);
    float l6 = base + DPN * (s1 + s5);
    float l7 = base + DPN * (s3 + s7);
    float l8 = base + DPN * (s5 + s7);

    float p0 = exp2f(fmaf(l0, LOG2E, -32.f));
    float p1 = exp2f(fmaf(l1, LOG2E, -32.f));
    float p2 = exp2f(fmaf(l2, LOG2E, -32.f));
    float p3 = exp2f(fmaf(l3, LOG2E, -32.f));
    float p4 = exp2f(fmaf(l4, LOG2E, -32.f));
    float p5 = exp2f(fmaf(l5, LOG2E, -32.f));
    float p6 = exp2f(fmaf(l6, LOG2E, -32.f));
    float p7 = exp2f(fmaf(l7, LOG2E, -32.f));
    float p8 = exp2f(fmaf(l8, LOG2E, -32.f));
    float ps = ((p0 + p1) + (p2 + p3)) + ((p4 + p5) + (p6 + p7)) + p8;

    // denominator reduce over 32-lane half: 2 DPP quad-perm adds + 3 shfl_xor
    float sv = act ? ps : 0.f;
    sv += __int_as_float(__builtin_amdgcn_update_dpp(0, __float_as_int(sv), 0xB1, 0xF, 0xF, true));
    sv += __int_as_float(__builtin_amdgcn_update_dpp(0, __float_as_int(sv), 0x4E, 0xF, 0xF, true));
    sv += __shfl_xor(sv, 4);
    sv += __shfl_xor(sv, 8);
    sv += __shfl_xor(sv, 16);
    if (kpl == 0 && q < 25) drow[q] = __builtin_amdgcn_rcpf(sv + 1e-35f);

    // per-offset fold coefficients (unscaled; rinv deferred to PV epilogue)
    float psm0 = ps - p0;
    float basec = -0.5f * psm0 - 0.375f * p0;
    float cv[9];
    cv[0] = basec + DPN * p3;
    cv[1] = basec + DPN * ((p1 + p5) + p6);
    cv[2] = basec + DPN * p4;
    cv[3] = basec + DPN * ((p2 + p5) + p7);
    cv[4] = 4.f * p0 + (4.f / 3.f) * psm0;
    cv[5] = basec + DPN * ((p2 + p6) + p8);
    cv[6] = basec + DPN * p4;
    cv[7] = basec + DPN * ((p1 + p7) + p8);
    cv[8] = basec + DPN * p3;

    // fold via bpermute: pass A -> pp = kpl, pass B -> pp = 32+kpl
    float a = 0.f, a2 = 0.f;
    #pragma unroll
    for (int j = 0; j < 9; ++j) {
      int cj = __float_as_int(cv[j]);
      a  = fmaf(selA[j], __int_as_float(__builtin_amdgcn_ds_bpermute(idxA[j], cj)), a);
      a2 = fmaf(selB[j], __int_as_float(__builtin_amdgcn_ds_bpermute(idxB[j], cj)), a2);
    }

    if (q < 25) {
      u16* arow = (u16*)((char*)SA + q * 272);
      u16 h1 = f2bf(a);
      arow[kpl]      = h1;
      arow[64 + kpl] = f2bf(a - bf2f(h1));
      u16 h2 = f2bf(a2);
      arow[32 + kpl] = h2;
      arow[96 + kpl] = f2bf(a2 - bf2f(h2));
    }
  }

  __syncthreads();   // single barrier: A/drow/vsT -> PV frag reads (alias-cast safety)

  // --- PV via MFMA (hi/lo compensated A), rinv epilogue ---
  {
    f32x4 o[2][2];
    #pragma unroll
    for (int i = 0; i < 2; ++i)
      #pragma unroll
      for (int j = 0; j < 2; ++j) o[i][j] = {0.f, 0.f, 0.f, 0.f};
    #pragma unroll
    for (int kx = 0; kx < 2; ++kx) {
      const int koff = kx * 64 + kgrp * 16;         // byte offset within hi block
      const char* sa = (const char*)SA;
      bf16x8 ah0 = *(const bf16x8*)(sa + cc * 272 + koff);
      bf16x8 ah1 = *(const bf16x8*)(sa + (cc + 16) * 272 + koff);
      bf16x8 al0 = *(const bf16x8*)(sa + cc * 272 + 128 + koff);
      bf16x8 al1 = *(const bf16x8*)(sa + (cc + 16) * 272 + 128 + koff);
      bf16x8 b0  = *(const bf16x8*)&vsT[cc * 72 + kx * 32 + ks8];
      bf16x8 b1  = *(const bf16x8*)&vsT[(cc + 16) * 72 + kx * 32 + ks8];
      o[0][0] = __builtin_amdgcn_mfma_f32_16x16x32_bf16(ah0, b0, o[0][0], 0, 0, 0);
      o[0][0] = __builtin_amdgcn_mfma_f32_16x16x32_bf16(al0, b0, o[0][0], 0, 0, 0);
      o[0][1] = __builtin_amdgcn_mfma_f32_16x16x32_bf16(ah0, b1, o[0][1], 0, 0, 0);
      o[0][1] = __builtin_amdgcn_mfma_f32_16x16x32_bf16(al0, b1, o[0][1], 0, 0, 0);
      o[1][0] = __builtin_amdgcn_mfma_f32_16x16x32_bf16(ah1, b0, o[1][0], 0, 0, 0);
      o[1][0] = __builtin_amdgcn_mfma_f32_16x16x32_bf16(al1, b0, o[1][0], 0, 0, 0);
      o[1][1] = __builtin_amdgcn_mfma_f32_16x16x32_bf16(ah1, b1, o[1][1], 0, 0, 0);
      o[1][1] = __builtin_amdgcn_mfma_f32_16x16x32_bf16(al1, b1, o[1][1], 0, 0, 0);
    }
    #pragma unroll
    for (int mt = 0; mt < 2; ++mt) {
      float4 rv = *(const float4*)&drow[mt * 16 + r0];
      #pragma unroll
      for (int i = 0; i < 4; ++i) {
        int q = mt * 16 + r0 + i;
        if (q < 25) {
          int qy = (q * 13) >> 6, qx = q - qy * 5;
          u16* dst = AO + gbase + ((size_t)((y0 + qy) * IMGW + x0 + qx)) * 32;
          float r = (&rv.x)[i];
          dst[cc]      = f2bf(o[mt][0][i] * r);
          dst[cc + 16] = f2bf(o[mt][1][i] * r);
        }
      }
    }
  }
}

// ---------------- K3: output projection via MFMA ----------------
__global__ __launch_bounds__(256) void outmm_kernel(
    const u16* __restrict__ AOb, const u16* __restrict__ Wb,
    const float* __restrict__ bout, float* __restrict__ O)
{
  __shared__ u16 Ws[256 * 40];
  __shared__ u16 Xs[64 * 40];
  const int t = threadIdx.x;
  const int lane = t & 63, wv = t >> 6;
  const int p0 = blockIdx.x * 64;
  const int b  = blockIdx.y;
  const u16* Wm = Wb + (size_t)3 * 65536;

  f32x4 acc[4][4];
  #pragma unroll
  for (int i = 0; i < 4; ++i)
    #pragma unroll
    for (int j = 0; j < 4; ++j) acc[i][j] = {0.f, 0.f, 0.f, 0.f};

  for (int kk = 0; kk < 8; ++kk) {
    #pragma unroll
    for (int p = 0; p < 4; ++p) {
      int fl = t + 256 * p;
      int d = fl >> 2, c = fl & 3;
      uint4 u = *(const uint4*)(Wm + d * 256 + kk * 32 + c * 8);
      *(uint4*)&Ws[d * 40 + c * 8] = u;
    }
    {
      int pix = t >> 2, c = t & 3;
      uint4 u = *(const uint4*)(AOb + ((size_t)(b * 8 + kk) * NPIX + p0 + pix) * 32 + c * 8);
      *(uint4*)&Xs[pix * 40 + c * 8] = u;
    }
    __syncthreads();
    bf16x8 af[4], bfr[4];
    #pragma unroll
    for (int f = 0; f < 4; ++f)
      af[f] = *(const bf16x8*)&Ws[(wv * 64 + f * 16 + (lane & 15)) * 40 + (lane >> 4) * 8];
    #pragma unroll
    for (int f = 0; f < 4; ++f)
      bfr[f] = *(const bf16x8*)&Xs[(f * 16 + (lane & 15)) * 40 + (lane >> 4) * 8];
    #pragma unroll
    for (int df = 0; df < 4; ++df)
      #pragma unroll
      for (int pf = 0; pf < 4; ++pf)
        acc[df][pf] = __builtin_amdgcn_mfma_f32_16x16x32_bf16(af[df], bfr[pf], acc[df][pf], 0, 0, 0);
    __syncthreads();
  }

  #pragma unroll
  for (int df = 0; df < 4; ++df) {
    int dim0 = wv * 64 + df * 16 + (lane >> 4) * 4;
    float4 bv = *(const float4*)&bout[dim0];
    #pragma unroll
    for (int pf = 0; pf < 4; ++pf) {
      int pix = p0 + pf * 16 + (lane & 15);
      f32x4 v = acc[df][pf];
      float* ob = O + (size_t)b * 256 * NPIX + pix;
      ob[(size_t)(dim0 + 0) * NPIX] = v[0] + bv.x;
      ob[(size_t)(dim0 + 1) * NPIX] = v[1] + bv.y;
      ob[(size_t)(dim0 + 2) * NPIX] = v[2] + bv.z;
      ob[(size_t)(dim0 + 3) * NPIX] = v[3] + bv.w;
    }
  }
}

extern "C" void kernel_launch(void* const* d_in, const int* in_sizes, int n_in,
                              void* d_out, int out_size, void* d_ws, size_t ws_size,
                              hipStream_t stream) {
  const float* x    = (const float*)d_in[0];
  const float* Wk   = (const float*)d_in[2];
  const float* Wv   = (const float*)d_in[3];
  const float* Wq   = (const float*)d_in[4];
  const float* Wout = (const float*)d_in[5];
  const float* bout = (const float*)d_in[6];

  // d_out: x_t bf16 (29,491,200 B) | Qb bf16 (29,491,200 B) — exact fit
  u16* x_t = (u16*)d_out;
  u16* Qb  = x_t + (size_t)4 * NPIX * 256;
  // ws: Kb | Vb | AOb (bf16) | Wb
  u16* Kb  = (u16*)d_ws;
  u16* Vb  = Kb + (size_t)4 * NPIX * 256;
  u16* AOb = Vb + (size_t)4 * NPIX * 256;
  u16* Wb  = AOb + (size_t)4 * NPIX * 256;

  wconv_kernel<<<dim3(64, 4), 256, 0, stream>>>(Wq, Wk, Wv, Wout, Wb);
  xpose_kernel<<<dim3(225, 4, 4), 256, 0, stream>>>(x, x_t);
  projmm_kernel<<<dim3(225, 4, 3), 256, 0, stream>>>(x_t, Wb, Qb, Kb, Vb);
  attn_kernel<<<dim3(18432), 64, 0, stream>>>(Qb, Kb, Vb, AOb);
  outmm_kernel<<<dim3(225, 4), 256, 0, stream>>>(AOb, Wb, bout, (float*)d_out);
}